// Round 1
// baseline (3071.300 us; speedup 1.0000x reference)
//
#include <hip/hip_runtime.h>

#define NPTS 4096
#define BNROWS 16384

__device__ __forceinline__ float lrelu(float h) { return h > 0.f ? h : 0.2f * h; }

// ---------------- bitonic helpers (block-wide, uniform barriers) ----------------
template<int M, int GSIZE>
__device__ inline void bitonic_idx(int* a, int gtid) {
  for (int k = 2; k <= M; k <<= 1) {
    for (int j = k >> 1; j > 0; j >>= 1) {
      __syncthreads();
      for (int i = gtid; i < M; i += GSIZE) {
        int ixj = i ^ j;
        if (ixj > i) {
          int va = a[i], vb = a[ixj];
          bool up = ((i & k) == 0);
          if ((va > vb) == up) { a[i] = vb; a[ixj] = va; }
        }
      }
    }
  }
  __syncthreads();
}

template<int M, int GSIZE>
__device__ inline void bitonic_pairs(unsigned long long* key, int* idx, int gtid) {
  for (int k = 2; k <= M; k <<= 1) {
    for (int j = k >> 1; j > 0; j >>= 1) {
      __syncthreads();
      for (int i = gtid; i < M; i += GSIZE) {
        int ixj = i ^ j;
        if (ixj > i) {
          unsigned long long ka = key[i], kb = key[ixj];
          int ia = idx[i], ib = idx[ixj];
          bool agtb = (ka > kb) || (ka == kb && ia > ib);
          bool up = ((i & k) == 0);
          if (agtb == up) { key[i] = kb; key[ixj] = ka; idx[i] = ib; idx[ixj] = ia; }
        }
      }
    }
  }
  __syncthreads();
}

// radix select: indices of the KSEL smallest of n u32 keys (ties at the kth key
// resolved by smallest index). selIdx[0..KSEL) filled (unsorted). Fixed 4 passes
// so that multiple groups in one block stay barrier-uniform.
template<int GSIZE>
__device__ inline void radix_select_idx(const unsigned int* keys, int n, int KSEL,
    unsigned int* hist, int* candIdx, int* selIdx, unsigned int* ctrl, int gtid)
{
  if (gtid == 0) { ctrl[0] = 0u; ctrl[1] = 0u; }
  for (int pass = 0; pass < 4; ++pass) {
    int shift = 24 - 8 * pass;
    for (int i = gtid; i < 256; i += GSIZE) hist[i] = 0u;
    __syncthreads();
    unsigned int prefix = ctrl[0];
    for (int j = gtid; j < n; j += GSIZE) {
      unsigned int k = keys[j];
      bool m = (pass == 0) ? true : ((k >> (shift + 8)) == prefix);
      if (m) atomicAdd(&hist[(k >> shift) & 255u], 1u);
    }
    __syncthreads();
    if (gtid == 0) {
      unsigned int c = ctrl[1];
      unsigned int b = 0;
      for (; b < 256u; ++b) { unsigned int h = hist[b]; if (c + h >= (unsigned int)KSEL) break; c += h; }
      ctrl[0] = (prefix << 8) | b;
      ctrl[1] = c;
    }
    __syncthreads();
  }
  unsigned int kth = ctrl[0], cntLess = ctrl[1];
  if (gtid == 0) { ctrl[2] = 0u; ctrl[3] = 0u; }
  __syncthreads();
  for (int j = gtid; j < n; j += GSIZE) {
    unsigned int k = keys[j];
    if (k < kth)      { unsigned int p = atomicAdd(&ctrl[2], 1u); selIdx[p] = j; }
    else if (k == kth){ unsigned int p = atomicAdd(&ctrl[3], 1u); if (p < 256u) candIdx[p] = j; }
  }
  __syncthreads();
  int nc = (int)ctrl[3];
  for (int i = gtid; i < 256; i += GSIZE) if (i >= nc) candIdx[i] = 0x7fffffff;
  __syncthreads();
  bitonic_idx<256, GSIZE>(candIdx, gtid);
  int rem = KSEL - (int)cntLess;
  for (int i = gtid; i < rem; i += GSIZE) selIdx[(int)cntLess + i] = candIdx[i];
  __syncthreads();
}

// ---------------- K1: pos 128-NN (sorted) + idx_pos ----------------
__global__ __launch_bounds__(256) void knn_pos_kernel(
    const float* __restrict__ pos, int* __restrict__ idx_l,
    int* __restrict__ idx1_i, float* __restrict__ idx1_f)
{
  __shared__ unsigned int keys[NPTS];
  __shared__ unsigned int hist[256];
  __shared__ int candIdx[256];
  __shared__ int selIdx[160];
  __shared__ unsigned long long rKey[256];
  __shared__ int rIdx[256];
  __shared__ unsigned int ctrl[8];
  int tid = threadIdx.x;
  int r = blockIdx.x;
  int b = r >> 12, n = r & 4095;
  const float* pb = pos + (size_t)b * NPTS * 3;
  float cx = pb[n*3+0], cy = pb[n*3+1], cz = pb[n*3+2];
  for (int j = tid; j < NPTS; j += 256) {
    float dx = cx - pb[j*3+0];
    float dy = cy - pb[j*3+1];
    float dz = cz - pb[j*3+2];
    float d2 = dx*dx + dy*dy + dz*dz;
    keys[j] = __float_as_uint(d2);
  }
  __syncthreads();
  radix_select_idx<256>(keys, NPTS, 160, hist, candIdx, selIdx, ctrl, tid);
  double cxd = (double)cx, cyd = (double)cy, czd = (double)cz;
  for (int i = tid; i < 256; i += 256) {
    if (i < 160) {
      int j = selIdx[i];
      double dx = cxd - (double)pb[j*3+0];
      double dy = cyd - (double)pb[j*3+1];
      double dz = czd - (double)pb[j*3+2];
      double d2 = dx*dx + dy*dy + dz*dz;
      rKey[i] = (unsigned long long)__double_as_longlong(d2);
      rIdx[i] = j;
    } else { rKey[i] = ~0ull; rIdx[i] = 0x7fffffff; }
  }
  __syncthreads();
  bitonic_pairs<256, 256>(rKey, rIdx, tid);
  for (int i = tid; i < 128; i += 256) idx_l[(size_t)r * 128 + i] = rIdx[i];
  if (tid < 6) {
    int v = rIdx[1 + tid];
    idx1_i[r * 14 + 8 + tid] = v;
    idx1_f[r * 14 + 8 + tid] = (float)v;
  }
}

// ---------------- K2: feature 8-NN (excl self), 4 rows per block ----------------
__global__ __launch_bounds__(512) void knn_feat_kernel(
    const float* __restrict__ x, int* __restrict__ idx1_i, float* __restrict__ idx1_f)
{
  __shared__ unsigned int keys[4][NPTS];
  __shared__ unsigned int hist[4][256];
  __shared__ int candIdx[4][256];
  __shared__ int selIdx[4][16];
  __shared__ unsigned long long rKey[4][16];
  __shared__ int rIdx[4][16];
  __shared__ unsigned int ctrl[4][8];
  __shared__ float ctrf[4][16];
  int tid = threadIdx.x;
  int g = tid >> 7, gtid = tid & 127;
  int rbase = blockIdx.x * 4;
  int b = rbase >> 12;
  const float* xb = x + (size_t)b * NPTS * 16;
  if (tid < 64) {
    int gg = tid >> 4, c = tid & 15;
    int nn = (rbase + gg) & 4095;
    ctrf[gg][c] = xb[(size_t)nn * 16 + c];
  }
  __syncthreads();
  for (int i = 0; i < 8; ++i) {
    int j = tid + 512 * i;
    const float4* xj = (const float4*)(xb + (size_t)j * 16);
    float4 a0 = xj[0], a1 = xj[1], a2 = xj[2], a3 = xj[3];
    float v[16] = {a0.x,a0.y,a0.z,a0.w, a1.x,a1.y,a1.z,a1.w,
                   a2.x,a2.y,a2.z,a2.w, a3.x,a3.y,a3.z,a3.w};
    #pragma unroll
    for (int gg = 0; gg < 4; ++gg) {
      float acc = 0.f;
      #pragma unroll
      for (int c = 0; c < 16; ++c) { float d = ctrf[gg][c] - v[c]; acc += d * d; }
      keys[gg][j] = __float_as_uint(acc);
    }
  }
  __syncthreads();
  radix_select_idx<128>(keys[g], NPTS, 16, hist[g], candIdx[g], selIdx[g], ctrl[g], gtid);
  if (gtid < 16) {
    int j = selIdx[g][gtid];
    const float* xj = xb + (size_t)j * 16;
    double acc = 0.0;
    #pragma unroll
    for (int c = 0; c < 16; ++c) { double d = (double)ctrf[g][c] - (double)xj[c]; acc += d * d; }
    rKey[g][gtid] = (unsigned long long)__double_as_longlong(acc);
    rIdx[g][gtid] = j;
  }
  __syncthreads();
  bitonic_pairs<16, 128>(rKey[g], rIdx[g], gtid);
  int r = rbase + g;
  if (gtid < 8) {
    int v = rIdx[g][1 + gtid];
    idx1_i[r * 14 + gtid] = v;
    idx1_f[r * 14 + gtid] = (float)v;
  }
}

// ---------------- K3: FPS (replicates the reference's batch-0 gather) ----------------
__global__ __launch_bounds__(256) void fps_kernel(
    const float* __restrict__ pos, const int* __restrict__ idx_l, int* __restrict__ idx_fps)
{
  int wave = threadIdx.x >> 6, lane = threadIdx.x & 63;
  int r = blockIdx.x * 4 + wave;
  const int* il = idx_l + (size_t)r * 128;
  int gi0 = il[lane], gi1 = il[lane + 64];
  // NOTE: reference indexes pos.reshape(B*N,3) with per-batch indices -> batch 0 coords.
  double x0 = (double)pos[gi0*3+0], y0 = (double)pos[gi0*3+1], z0 = (double)pos[gi0*3+2];
  double x1 = (double)pos[gi1*3+0], y1 = (double)pos[gi1*3+1], z1 = (double)pos[gi1*3+2];
  double d0 = 1e10, d1 = 1e10;
  int far = 0;
  int* outp = idx_fps + (size_t)r * 32;
  for (int i = 0; i < 32; ++i) {
    int ownerLane = far & 63;
    int sel = far >> 6;
    int gsel = sel ? gi1 : gi0;
    int gout = __shfl(gsel, ownerLane, 64);
    if (lane == 0) outp[i] = gout;
    double cx = __shfl(sel ? x1 : x0, ownerLane, 64);
    double cy = __shfl(sel ? y1 : y0, ownerLane, 64);
    double cz = __shfl(sel ? z1 : z0, ownerLane, 64);
    double t0 = (x0-cx)*(x0-cx) + (y0-cy)*(y0-cy) + (z0-cz)*(z0-cz);
    double t1 = (x1-cx)*(x1-cx) + (y1-cy)*(y1-cy) + (z1-cz)*(z1-cz);
    d0 = fmin(d0, t0); d1 = fmin(d1, t1);
    double v; int p;
    if (d1 > d0) { v = d1; p = lane + 64; } else { v = d0; p = lane; }
    for (int off = 32; off > 0; off >>= 1) {
      double ov = __shfl_xor(v, off, 64);
      int op = __shfl_xor(p, off, 64);
      if (ov > v || (ov == v && op < p)) { v = ov; p = op; }
    }
    far = p;
  }
}

// ---------------- K4: h1 pre-act stats + per-(b,n) channel max ----------------
__global__ __launch_bounds__(256) void h1_kernel(
    const float* __restrict__ x, const int* __restrict__ idx1_i, const float* __restrict__ W1,
    double* __restrict__ slotsH1, float* __restrict__ h1max)
{
  __shared__ float sW1t[1024];   // [c][o]
  __shared__ float nbr[224];
  __shared__ float ctr[16];
  __shared__ float hbuf[448];
  __shared__ float bsum[32], bss[32];
  int tid = threadIdx.x;
  int r = blockIdx.x, b = r >> 12;
  const float* xb = x + (size_t)b * NPTS * 16;
  for (int i = tid; i < 1024; i += 256) { int o = i >> 5, c = i & 31; sW1t[c * 32 + o] = W1[i]; }
  if (tid < 16) ctr[tid] = xb[(size_t)(r & 4095) * 16 + tid];
  if (tid < 32) { bsum[tid] = 0.f; bss[tid] = 0.f; }
  if (tid < 224) { int k = tid >> 4, c = tid & 15; int j = idx1_i[r * 14 + k]; nbr[tid] = xb[(size_t)j * 16 + c]; }
  __syncthreads();
  float ls = 0.f, lss = 0.f;
  for (int m = tid; m < 448; m += 256) {
    int k = m >> 5, o = m & 31;
    float acc = 0.f;
    #pragma unroll
    for (int c = 0; c < 16; ++c) acc += (nbr[k * 16 + c] - ctr[c]) * sW1t[c * 32 + o];
    #pragma unroll
    for (int c = 0; c < 16; ++c) acc += ctr[c] * sW1t[(16 + c) * 32 + o];
    hbuf[m] = acc;
    ls += acc; lss += acc * acc;
  }
  atomicAdd(&bsum[tid & 31], ls);
  atomicAdd(&bss[tid & 31], lss);
  __syncthreads();
  if (tid < 32) {
    float mx = hbuf[tid];
    #pragma unroll
    for (int k = 1; k < 14; ++k) mx = fmaxf(mx, hbuf[k * 32 + tid]);
    h1max[(size_t)r * 32 + tid] = mx;
    int slot = r & 255;
    atomicAdd(&slotsH1[slot * 64 + tid], (double)bsum[tid]);
    atomicAdd(&slotsH1[slot * 64 + 32 + tid], (double)bss[tid]);
  }
}

// ---------------- stats finalize: scsh = [sc(C), sh(C)] ----------------
__global__ void finalize_stats_kernel(const double* __restrict__ slots, int C, double cnt,
    const float* __restrict__ g, const float* __restrict__ bta, float* __restrict__ scsh)
{
  int o = threadIdx.x;
  if (o < C) {
    double s = 0.0, ss = 0.0;
    for (int slot = 0; slot < 256; ++slot) { s += slots[slot * 2 * C + o]; ss += slots[slot * 2 * C + C + o]; }
    double mu = s / cnt;
    double var = ss / cnt - mu * mu;
    double rs = 1.0 / sqrt(var + 1e-5);
    float sc = (float)rs * g[o];
    float sh = bta[o] - (float)mu * sc;
    scsh[o] = sc;
    scsh[C + o] = sh;
  }
}

// ---------------- f1 = lrelu(affine(h1max)) ----------------
__global__ void apply_f1_kernel(const float* __restrict__ h1max, const float* __restrict__ scsh,
                                float* __restrict__ f1)
{
  int i = blockIdx.x * 256 + threadIdx.x;
  int o = i & 31;
  f1[i] = lrelu(h1max[i] * scsh[o] + scsh[32 + o]);
}

// ---------------- K6: h2 pre-act stats only ----------------
__global__ __launch_bounds__(256) void h2_stats_kernel(
    const float* __restrict__ f1, const int* __restrict__ idx_fps, const float* __restrict__ W2,
    double* __restrict__ slotsH2)
{
  __shared__ float sW2t[4096];   // [c][o]
  __shared__ float nbr[1024];
  __shared__ float ctr[32];
  __shared__ int nid[32];
  __shared__ float bsum[64], bss[64];
  int tid = threadIdx.x;
  int r = blockIdx.x, b = r >> 12;
  const float* f1b = f1 + (size_t)b * NPTS * 32;
  for (int i = tid; i < 4096; i += 256) { int o = i >> 6, c = i & 63; sW2t[c * 64 + o] = W2[i]; }
  if (tid < 32) { ctr[tid] = f1[(size_t)r * 32 + tid]; nid[tid] = idx_fps[r * 32 + tid]; }
  if (tid < 64) { bsum[tid] = 0.f; bss[tid] = 0.f; }
  __syncthreads();
  for (int t = tid; t < 1024; t += 256) { int k = t >> 5, c = t & 31; nbr[t] = f1b[(size_t)nid[k] * 32 + c]; }
  __syncthreads();
  float ls = 0.f, lss = 0.f;
  for (int m = tid; m < 2048; m += 256) {
    int k = m >> 6, o = m & 63;
    float acc = 0.f;
    #pragma unroll
    for (int c = 0; c < 32; ++c) acc += (nbr[k * 32 + c] - ctr[c]) * sW2t[c * 64 + o];
    #pragma unroll
    for (int c = 0; c < 32; ++c) acc += ctr[c] * sW2t[(32 + c) * 64 + o];
    ls += acc; lss += acc * acc;
  }
  atomicAdd(&bsum[tid & 63], ls);
  atomicAdd(&bss[tid & 63], lss);
  __syncthreads();
  if (tid < 64) {
    int slot = r & 255;
    atomicAdd(&slotsH2[slot * 128 + tid], (double)bsum[tid]);
    atomicAdd(&slotsH2[slot * 128 + 64 + tid], (double)bss[tid]);
  }
}

// ---------------- K8: recompute h2, BN+lrelu, h3 pre-act stats + channel max ----------------
__global__ __launch_bounds__(256) void h3_kernel(
    const float* __restrict__ f1, const int* __restrict__ idx_fps,
    const float* __restrict__ W2, const float* __restrict__ W3, const float* __restrict__ scsh2,
    double* __restrict__ slotsH3, float* __restrict__ h3max)
{
  __shared__ float sW2t[4096];
  __shared__ float sW3t[4096];
  __shared__ float nbr[1024];
  __shared__ float ctr[32];
  __shared__ int nid[32];
  __shared__ float h2post[2048];
  __shared__ float h3buf[2048];
  __shared__ float ssc[64], ssh[64];
  __shared__ float bsum[64], bss[64];
  int tid = threadIdx.x;
  int r = blockIdx.x, b = r >> 12;
  const float* f1b = f1 + (size_t)b * NPTS * 32;
  for (int i = tid; i < 4096; i += 256) {
    int o = i >> 6, c = i & 63;
    sW2t[c * 64 + o] = W2[i];
    sW3t[c * 64 + o] = W3[i];
  }
  if (tid < 32) { ctr[tid] = f1[(size_t)r * 32 + tid]; nid[tid] = idx_fps[r * 32 + tid]; }
  if (tid < 64) { bsum[tid] = 0.f; bss[tid] = 0.f; ssc[tid] = scsh2[tid]; ssh[tid] = scsh2[64 + tid]; }
  __syncthreads();
  for (int t = tid; t < 1024; t += 256) { int k = t >> 5, c = t & 31; nbr[t] = f1b[(size_t)nid[k] * 32 + c]; }
  __syncthreads();
  for (int m = tid; m < 2048; m += 256) {
    int k = m >> 6, o = m & 63;
    float acc = 0.f;
    #pragma unroll
    for (int c = 0; c < 32; ++c) acc += (nbr[k * 32 + c] - ctr[c]) * sW2t[c * 64 + o];
    #pragma unroll
    for (int c = 0; c < 32; ++c) acc += ctr[c] * sW2t[(32 + c) * 64 + o];
    h2post[m] = lrelu(acc * ssc[o] + ssh[o]);
  }
  __syncthreads();
  float ls = 0.f, lss = 0.f;
  for (int m = tid; m < 2048; m += 256) {
    int k = m >> 6, o = m & 63;
    float acc = 0.f;
    #pragma unroll
    for (int h = 0; h < 64; ++h) acc += h2post[k * 64 + h] * sW3t[h * 64 + o];
    h3buf[m] = acc;
    ls += acc; lss += acc * acc;
  }
  atomicAdd(&bsum[tid & 63], ls);
  atomicAdd(&bss[tid & 63], lss);
  __syncthreads();
  if (tid < 64) {
    float mx = h3buf[tid];
    #pragma unroll
    for (int k = 1; k < 32; ++k) mx = fmaxf(mx, h3buf[k * 64 + tid]);
    h3max[(size_t)r * 64 + tid] = mx;
    int slot = r & 255;
    atomicAdd(&slotsH3[slot * 128 + tid], (double)bsum[tid]);
    atomicAdd(&slotsH3[slot * 128 + 64 + tid], (double)bss[tid]);
  }
}

// ---------------- K10: out = lrelu(affine(h3max)) ----------------
__global__ void out_kernel(const float* __restrict__ h3max, const float* __restrict__ scsh3,
                           float* __restrict__ out)
{
  int i = blockIdx.x * 256 + threadIdx.x;
  int o = i & 63;
  out[i] = lrelu(h3max[i] * scsh3[o] + scsh3[64 + o]);
}

extern "C" void kernel_launch(void* const* d_in, const int* in_sizes, int n_in,
                              void* d_out, int out_size, void* d_ws, size_t ws_size,
                              hipStream_t stream) {
  (void)in_sizes; (void)n_in; (void)out_size; (void)ws_size;
  const float* x   = (const float*)d_in[0];
  const float* pos = (const float*)d_in[1];
  const float* W1  = (const float*)d_in[2];
  const float* g1  = (const float*)d_in[3];
  const float* b1  = (const float*)d_in[4];
  const float* W2  = (const float*)d_in[5];
  const float* g2  = (const float*)d_in[6];
  const float* b2  = (const float*)d_in[7];
  const float* W3  = (const float*)d_in[8];
  const float* g3  = (const float*)d_in[9];
  const float* b3  = (const float*)d_in[10];

  float* out      = (float*)d_out;             // (4,4096,64) f32
  float* out_idx1 = out + 1048576;             // (4,4096,14) written as float(idx)

  char* ws = (char*)d_ws;
  double* slotsH1 = (double*)(ws + 0);         // 256 x 64 double
  double* slotsH2 = (double*)(ws + 131072);    // 256 x 128 double
  double* slotsH3 = (double*)(ws + 393216);    // 256 x 128 double
  float*  scsh1   = (float*)(ws + 655360);     // 64 f
  float*  scsh2   = (float*)(ws + 655616);     // 128 f
  float*  scsh3   = (float*)(ws + 656128);     // 128 f
  int*    idx_l   = (int*)(ws + 1048576);      // 16384 x 128
  int*    idx_fps = (int*)(ws + 9437184);      // 16384 x 32
  int*    idx1_i  = (int*)(ws + 11534336);     // 16384 x 14
  float*  h1max   = (float*)(ws + 12451840);   // 16384 x 32
  float*  f1      = (float*)(ws + 14548992);   // 16384 x 32
  float*  h3max   = (float*)(ws + 16646144);   // 16384 x 64

  hipMemsetAsync(d_ws, 0, 656640, stream);     // zero stat accumulators

  knn_pos_kernel <<<dim3(16384), dim3(256), 0, stream>>>(pos, idx_l, idx1_i, out_idx1);
  knn_feat_kernel<<<dim3(4096),  dim3(512), 0, stream>>>(x, idx1_i, out_idx1);
  fps_kernel     <<<dim3(4096),  dim3(256), 0, stream>>>(pos, idx_l, idx_fps);
  h1_kernel      <<<dim3(16384), dim3(256), 0, stream>>>(x, idx1_i, W1, slotsH1, h1max);
  finalize_stats_kernel<<<dim3(1), dim3(64), 0, stream>>>(slotsH1, 32, 229376.0, g1, b1, scsh1);
  apply_f1_kernel<<<dim3(2048),  dim3(256), 0, stream>>>(h1max, scsh1, f1);
  h2_stats_kernel<<<dim3(16384), dim3(256), 0, stream>>>(f1, idx_fps, W2, slotsH2);
  finalize_stats_kernel<<<dim3(1), dim3(64), 0, stream>>>(slotsH2, 64, 524288.0, g2, b2, scsh2);
  h3_kernel      <<<dim3(16384), dim3(256), 0, stream>>>(f1, idx_fps, W2, W3, scsh2, slotsH3, h3max);
  finalize_stats_kernel<<<dim3(1), dim3(64), 0, stream>>>(slotsH3, 64, 524288.0, g3, b3, scsh3);
  out_kernel     <<<dim3(4096),  dim3(256), 0, stream>>>(h3max, scsh3, out);
}

// Round 2
// 1817.053 us; speedup vs baseline: 1.6903x; 1.6903x over previous
//
#include <hip/hip_runtime.h>

#define NPTS 4096
#define BNROWS 16384

__device__ __forceinline__ float lrelu(float h) { return h > 0.f ? h : 0.2f * h; }

// ---------------- bitonic helpers (block-wide, uniform barriers) ----------------
template<int M, int GSIZE>
__device__ inline void bitonic_idx(int* a, int gtid) {
  for (int k = 2; k <= M; k <<= 1) {
    for (int j = k >> 1; j > 0; j >>= 1) {
      __syncthreads();
      for (int i = gtid; i < M; i += GSIZE) {
        int ixj = i ^ j;
        if (ixj > i) {
          int va = a[i], vb = a[ixj];
          bool up = ((i & k) == 0);
          if ((va > vb) == up) { a[i] = vb; a[ixj] = va; }
        }
      }
    }
  }
  __syncthreads();
}

template<int M, int GSIZE>
__device__ inline void bitonic_pairs(unsigned long long* key, int* idx, int gtid) {
  for (int k = 2; k <= M; k <<= 1) {
    for (int j = k >> 1; j > 0; j >>= 1) {
      __syncthreads();
      for (int i = gtid; i < M; i += GSIZE) {
        int ixj = i ^ j;
        if (ixj > i) {
          unsigned long long ka = key[i], kb = key[ixj];
          int ia = idx[i], ib = idx[ixj];
          bool agtb = (ka > kb) || (ka == kb && ia > ib);
          bool up = ((i & k) == 0);
          if (agtb == up) { key[i] = kb; key[ixj] = ka; idx[i] = ib; idx[ixj] = ia; }
        }
      }
    }
  }
  __syncthreads();
}

// ---------------- K1: pos 128-NN (sorted) + idx_pos ----------------
// register-resident keys, u16 quantized 2-pass radix select, parallel scan
__global__ __launch_bounds__(256) void knn_pos_kernel(
    const float* __restrict__ pos, int* __restrict__ idx_l,
    int* __restrict__ idx1_i, float* __restrict__ idx1_f)
{
  __shared__ unsigned int hist[256];
  __shared__ int candIdx[256];
  __shared__ int selIdx[160];
  __shared__ unsigned long long rKey[256];
  __shared__ int rIdx[256];
  __shared__ unsigned int ctrl[8];
  __shared__ float redbuf[8];
  int tid = threadIdx.x;
  int r = blockIdx.x;
  int b = r >> 12, n = r & 4095;
  const float* pb = pos + (size_t)b * NPTS * 3;
  float cx = pb[n*3+0], cy = pb[n*3+1], cz = pb[n*3+2];
  float dkey[16];
  float mn = 3.4e38f, mx = 0.f;
  #pragma unroll
  for (int i = 0; i < 16; ++i) {
    int j = tid + 256 * i;
    float dx = cx - pb[j*3+0], dy = cy - pb[j*3+1], dz = cz - pb[j*3+2];
    float d2 = dx*dx + dy*dy + dz*dz;
    dkey[i] = d2;
    mn = fminf(mn, d2); mx = fmaxf(mx, d2);
  }
  #pragma unroll
  for (int off = 32; off > 0; off >>= 1) {
    mn = fminf(mn, __shfl_xor(mn, off, 64));
    mx = fmaxf(mx, __shfl_xor(mx, off, 64));
  }
  if ((tid & 63) == 0) { redbuf[tid >> 6] = mn; redbuf[4 + (tid >> 6)] = mx; }
  __syncthreads();
  mn = fminf(fminf(redbuf[0], redbuf[1]), fminf(redbuf[2], redbuf[3]));
  mx = fmaxf(fmaxf(redbuf[4], redbuf[5]), fmaxf(redbuf[6], redbuf[7]));
  unsigned int mnb = __float_as_uint(mn);
  unsigned int rng = __float_as_uint(mx) - mnb;
  int sh = (rng > 65535u) ? (16 - __clz(rng)) : 0;
  unsigned int q[16];
  #pragma unroll
  for (int i = 0; i < 16; ++i) q[i] = (__float_as_uint(dkey[i]) - mnb) >> sh;

  if (tid == 0) { ctrl[0] = 0u; ctrl[1] = 0u; ctrl[2] = 0u; ctrl[3] = 0u; }
  __syncthreads();
  for (int p = 0; p < 2; ++p) {
    hist[tid] = 0u;
    __syncthreads();
    unsigned int hb = ctrl[0], c0 = ctrl[1];
    if (p == 0) {
      #pragma unroll
      for (int i = 0; i < 16; ++i) atomicAdd(&hist[q[i] >> 8], 1u);
    } else {
      #pragma unroll
      for (int i = 0; i < 16; ++i) if ((q[i] >> 8) == hb) atomicAdd(&hist[q[i] & 255u], 1u);
    }
    __syncthreads();
    for (int d = 1; d < 256; d <<= 1) {
      unsigned int v = hist[tid] + ((tid >= d) ? hist[tid - d] : 0u);
      __syncthreads();
      hist[tid] = v;
      __syncthreads();
    }
    unsigned int cip = c0 + hist[tid];
    unsigned int cie = c0 + (tid ? hist[tid - 1] : 0u);
    if (cip >= 160u && cie < 160u) {
      ctrl[0] = (p == 0) ? (unsigned int)tid : ((hb << 8) | (unsigned int)tid);
      ctrl[1] = cie;
    }
    __syncthreads();
  }
  unsigned int kth = ctrl[0], cntLess = ctrl[1];
  #pragma unroll
  for (int i = 0; i < 16; ++i) {
    unsigned int k = q[i];
    int j = tid + 256 * i;
    if (k < kth)       { unsigned int p = atomicAdd(&ctrl[2], 1u); selIdx[p] = j; }
    else if (k == kth) { unsigned int p = atomicAdd(&ctrl[3], 1u); if (p < 256u) candIdx[p] = j; }
  }
  __syncthreads();
  int nc = (int)ctrl[3];
  if (tid >= nc) candIdx[tid] = 0x7fffffff;
  __syncthreads();
  bitonic_idx<256, 256>(candIdx, tid);
  int rem = 160 - (int)cntLess;
  if (tid < rem) selIdx[cntLess + tid] = candIdx[tid];
  __syncthreads();

  double cxd = (double)cx, cyd = (double)cy, czd = (double)cz;
  if (tid < 160) {
    int j = selIdx[tid];
    double dx = cxd - (double)pb[j*3+0];
    double dy = cyd - (double)pb[j*3+1];
    double dz = czd - (double)pb[j*3+2];
    double d2 = dx*dx + dy*dy + dz*dz;
    rKey[tid] = (unsigned long long)__double_as_longlong(d2);
    rIdx[tid] = j;
  } else { rKey[tid] = ~0ull; rIdx[tid] = 0x7fffffff; }
  __syncthreads();
  bitonic_pairs<256, 256>(rKey, rIdx, tid);
  if (tid < 128) idx_l[(size_t)r * 128 + tid] = rIdx[tid];
  if (tid < 6) {
    int v = rIdx[1 + tid];
    idx1_i[r * 14 + 8 + tid] = v;
    idx1_f[r * 14 + 8 + tid] = (float)v;
  }
}

// ---------------- K2: feature 8-NN (excl self), 4 rows per block ----------------
__global__ __launch_bounds__(512) void knn_feat_kernel(
    const float* __restrict__ x, int* __restrict__ idx1_i, float* __restrict__ idx1_f)
{
  __shared__ unsigned int hist[4][256];
  __shared__ int candIdx[4][256];
  __shared__ int selIdx[4][32];
  __shared__ unsigned long long rKey[4][32];
  __shared__ int rIdx[4][32];
  __shared__ unsigned int ctrl[4][4];
  __shared__ float ctrf[4][16];
  __shared__ float redmn[8][4], redmx[8][4];
  int tid = threadIdx.x;
  int wave = tid >> 6, lane = tid & 63;
  int rbase = blockIdx.x * 4;
  int b = rbase >> 12;
  const float* xb = x + (size_t)b * NPTS * 16;
  if (tid < 64) {
    int gg = tid >> 4, c = tid & 15;
    int nn = (rbase + gg) & 4095;
    ctrf[gg][c] = xb[(size_t)nn * 16 + c];
  }
  if (tid < 16) ((unsigned int*)ctrl)[tid] = 0u;
  __syncthreads();

  float dk[4][8];
  float gmn[4] = {3.4e38f, 3.4e38f, 3.4e38f, 3.4e38f};
  float gmx[4] = {0.f, 0.f, 0.f, 0.f};
  #pragma unroll
  for (int i = 0; i < 8; ++i) {
    int j = tid + 512 * i;
    const float4* xj = (const float4*)(xb + (size_t)j * 16);
    float4 a0 = xj[0], a1 = xj[1], a2 = xj[2], a3 = xj[3];
    float v[16] = {a0.x,a0.y,a0.z,a0.w, a1.x,a1.y,a1.z,a1.w,
                   a2.x,a2.y,a2.z,a2.w, a3.x,a3.y,a3.z,a3.w};
    #pragma unroll
    for (int g = 0; g < 4; ++g) {
      float acc = 0.f;
      #pragma unroll
      for (int c = 0; c < 16; ++c) { float d = ctrf[g][c] - v[c]; acc += d * d; }
      dk[g][i] = acc;
      gmn[g] = fminf(gmn[g], acc);
      gmx[g] = fmaxf(gmx[g], acc);
    }
  }
  #pragma unroll
  for (int off = 32; off > 0; off >>= 1) {
    #pragma unroll
    for (int g = 0; g < 4; ++g) {
      gmn[g] = fminf(gmn[g], __shfl_xor(gmn[g], off, 64));
      gmx[g] = fmaxf(gmx[g], __shfl_xor(gmx[g], off, 64));
    }
  }
  if (lane == 0) {
    #pragma unroll
    for (int g = 0; g < 4; ++g) { redmn[wave][g] = gmn[g]; redmx[wave][g] = gmx[g]; }
  }
  __syncthreads();
  unsigned int mnbg[4]; int shg[4];
  #pragma unroll
  for (int g = 0; g < 4; ++g) {
    float mn = redmn[0][g], mx = redmx[0][g];
    #pragma unroll
    for (int w = 1; w < 8; ++w) { mn = fminf(mn, redmn[w][g]); mx = fmaxf(mx, redmx[w][g]); }
    unsigned int mnb = __float_as_uint(mn);
    unsigned int rng = __float_as_uint(mx) - mnb;
    shg[g] = (rng > 65535u) ? (16 - __clz(rng)) : 0;
    mnbg[g] = mnb;
  }
  #define QV(g, i) ((__float_as_uint(dk[g][i]) - mnbg[g]) >> shg[g])

  for (int p = 0; p < 2; ++p) {
    for (int it = tid; it < 1024; it += 512) hist[it >> 8][it & 255] = 0u;
    __syncthreads();
    unsigned int hbg[4], c0g[4];
    #pragma unroll
    for (int g = 0; g < 4; ++g) { hbg[g] = ctrl[g][0]; c0g[g] = ctrl[g][1]; }
    if (p == 0) {
      #pragma unroll
      for (int g = 0; g < 4; ++g)
        #pragma unroll
        for (int i = 0; i < 8; ++i) atomicAdd(&hist[g][QV(g, i) >> 8], 1u);
    } else {
      #pragma unroll
      for (int g = 0; g < 4; ++g)
        #pragma unroll
        for (int i = 0; i < 8; ++i) {
          unsigned int qv = QV(g, i);
          if ((qv >> 8) == hbg[g]) atomicAdd(&hist[g][qv & 255u], 1u);
        }
    }
    __syncthreads();
    for (int d = 1; d < 256; d <<= 1) {
      int g0 = tid >> 8, i0 = tid & 255;
      int g1 = (tid + 512) >> 8, i1 = tid & 255;
      unsigned int v0 = hist[g0][i0] + ((i0 >= d) ? hist[g0][i0 - d] : 0u);
      unsigned int v1 = hist[g1][i1] + ((i1 >= d) ? hist[g1][i1 - d] : 0u);
      __syncthreads();
      hist[g0][i0] = v0; hist[g1][i1] = v1;
      __syncthreads();
    }
    for (int it = tid; it < 1024; it += 512) {
      int g = it >> 8, i = it & 255;
      unsigned int cip = c0g[g] + hist[g][i];
      unsigned int cie = c0g[g] + (i ? hist[g][i - 1] : 0u);
      if (cip >= 32u && cie < 32u) {
        ctrl[g][0] = (p == 0) ? (unsigned int)i : ((hbg[g] << 8) | (unsigned int)i);
        ctrl[g][1] = cie;
      }
    }
    __syncthreads();
  }
  unsigned int kthg[4], cLg[4];
  #pragma unroll
  for (int g = 0; g < 4; ++g) { kthg[g] = ctrl[g][0]; cLg[g] = ctrl[g][1]; }
  #pragma unroll
  for (int g = 0; g < 4; ++g) {
    #pragma unroll
    for (int i = 0; i < 8; ++i) {
      unsigned int k = QV(g, i);
      int j = tid + 512 * i;
      if (k < kthg[g])       { unsigned int p = atomicAdd(&ctrl[g][2], 1u); selIdx[g][p] = j; }
      else if (k == kthg[g]) { unsigned int p = atomicAdd(&ctrl[g][3], 1u); if (p < 256u) candIdx[g][p] = j; }
    }
  }
  __syncthreads();
  for (int it = tid; it < 1024; it += 512) {
    int g = it >> 8, i = it & 255;
    if (i >= (int)ctrl[g][3]) candIdx[g][i] = 0x7fffffff;
  }
  __syncthreads();
  for (int k = 2; k <= 256; k <<= 1) {
    for (int j2 = k >> 1; j2 > 0; j2 >>= 1) {
      __syncthreads();
      for (int it = tid; it < 1024; it += 512) {
        int g = it >> 8, i = it & 255, ixj = i ^ j2;
        if (ixj > i) {
          int va = candIdx[g][i], vb = candIdx[g][ixj];
          bool up = ((i & k) == 0);
          if ((va > vb) == up) { candIdx[g][i] = vb; candIdx[g][ixj] = va; }
        }
      }
    }
  }
  __syncthreads();
  if (tid < 128) {
    int g = tid >> 5, i = tid & 31;
    int rem = 32 - (int)cLg[g];
    if (i < rem) selIdx[g][cLg[g] + i] = candIdx[g][i];
  }
  __syncthreads();
  if (tid < 128) {
    int g = tid >> 5, i = tid & 31;
    int j = selIdx[g][i];
    const float* xj = xb + (size_t)j * 16;
    double acc = 0.0;
    #pragma unroll
    for (int c = 0; c < 16; ++c) { double d = (double)ctrf[g][c] - (double)xj[c]; acc += d * d; }
    rKey[g][i] = (unsigned long long)__double_as_longlong(acc);
    rIdx[g][i] = j;
  }
  for (int k = 2; k <= 32; k <<= 1) {
    for (int j2 = k >> 1; j2 > 0; j2 >>= 1) {
      __syncthreads();
      if (tid < 128) {
        int g = tid >> 5, i = tid & 31, ixj = i ^ j2;
        if (ixj > i) {
          unsigned long long ka = rKey[g][i], kb = rKey[g][ixj];
          int ia = rIdx[g][i], ib = rIdx[g][ixj];
          bool agtb = (ka > kb) || (ka == kb && ia > ib);
          bool up = ((i & k) == 0);
          if (agtb == up) { rKey[g][i] = kb; rKey[g][ixj] = ka; rIdx[g][i] = ib; rIdx[g][ixj] = ia; }
        }
      }
    }
  }
  __syncthreads();
  if (tid < 32) {
    int g = tid >> 3, i = tid & 7;
    int r = rbase + g;
    int v = rIdx[g][1 + i];
    idx1_i[r * 14 + i] = v;
    idx1_f[r * 14 + i] = (float)v;
  }
  #undef QV
}

// ---------------- K3: FPS (replicates the reference's batch-0 gather) ----------------
__global__ __launch_bounds__(256) void fps_kernel(
    const float* __restrict__ pos, const int* __restrict__ idx_l, int* __restrict__ idx_fps)
{
  int wave = threadIdx.x >> 6, lane = threadIdx.x & 63;
  int r = blockIdx.x * 4 + wave;
  const int* il = idx_l + (size_t)r * 128;
  int gi0 = il[lane], gi1 = il[lane + 64];
  double x0 = (double)pos[gi0*3+0], y0 = (double)pos[gi0*3+1], z0 = (double)pos[gi0*3+2];
  double x1 = (double)pos[gi1*3+0], y1 = (double)pos[gi1*3+1], z1 = (double)pos[gi1*3+2];
  double d0 = 1e10, d1 = 1e10;
  int far = 0;
  int* outp = idx_fps + (size_t)r * 32;
  for (int i = 0; i < 32; ++i) {
    int ownerLane = far & 63;
    int sel = far >> 6;
    int gsel = sel ? gi1 : gi0;
    int gout = __shfl(gsel, ownerLane, 64);
    if (lane == 0) outp[i] = gout;
    double cx = __shfl(sel ? x1 : x0, ownerLane, 64);
    double cy = __shfl(sel ? y1 : y0, ownerLane, 64);
    double cz = __shfl(sel ? z1 : z0, ownerLane, 64);
    double t0 = (x0-cx)*(x0-cx) + (y0-cy)*(y0-cy) + (z0-cz)*(z0-cz);
    double t1 = (x1-cx)*(x1-cx) + (y1-cy)*(y1-cy) + (z1-cz)*(z1-cz);
    d0 = fmin(d0, t0); d1 = fmin(d1, t1);
    double v; int p;
    if (d1 > d0) { v = d1; p = lane + 64; } else { v = d0; p = lane; }
    for (int off = 32; off > 0; off >>= 1) {
      double ov = __shfl_xor(v, off, 64);
      int op = __shfl_xor(p, off, 64);
      if (ov > v || (ov == v && op < p)) { v = ov; p = op; }
    }
    far = p;
  }
}

// ---------------- K4: h1 pre-act stats + per-(b,n) channel max ----------------
__global__ __launch_bounds__(256) void h1_kernel(
    const float* __restrict__ x, const int* __restrict__ idx1_i, const float* __restrict__ W1,
    double* __restrict__ slotsH1, float* __restrict__ h1max)
{
  __shared__ float sW1t[1024];   // [c][o]
  __shared__ float nbr[224];
  __shared__ float ctr[16];
  __shared__ float hbuf[448];
  __shared__ float bsum[32], bss[32];
  int tid = threadIdx.x;
  int r = blockIdx.x, b = r >> 12;
  const float* xb = x + (size_t)b * NPTS * 16;
  for (int i = tid; i < 1024; i += 256) { int o = i >> 5, c = i & 31; sW1t[c * 32 + o] = W1[i]; }
  if (tid < 16) ctr[tid] = xb[(size_t)(r & 4095) * 16 + tid];
  if (tid < 32) { bsum[tid] = 0.f; bss[tid] = 0.f; }
  if (tid < 224) { int k = tid >> 4, c = tid & 15; int j = idx1_i[r * 14 + k]; nbr[tid] = xb[(size_t)j * 16 + c]; }
  __syncthreads();
  float ls = 0.f, lss = 0.f;
  for (int m = tid; m < 448; m += 256) {
    int k = m >> 5, o = m & 31;
    float acc = 0.f;
    #pragma unroll
    for (int c = 0; c < 16; ++c) acc += (nbr[k * 16 + c] - ctr[c]) * sW1t[c * 32 + o];
    #pragma unroll
    for (int c = 0; c < 16; ++c) acc += ctr[c] * sW1t[(16 + c) * 32 + o];
    hbuf[m] = acc;
    ls += acc; lss += acc * acc;
  }
  atomicAdd(&bsum[tid & 31], ls);
  atomicAdd(&bss[tid & 31], lss);
  __syncthreads();
  if (tid < 32) {
    float mx = hbuf[tid];
    #pragma unroll
    for (int k = 1; k < 14; ++k) mx = fmaxf(mx, hbuf[k * 32 + tid]);
    h1max[(size_t)r * 32 + tid] = mx;
    int slot = r & 255;
    atomicAdd(&slotsH1[slot * 64 + tid], (double)bsum[tid]);
    atomicAdd(&slotsH1[slot * 64 + 32 + tid], (double)bss[tid]);
  }
}

// ---------------- stats finalize: scsh = [sc(C), sh(C)] ----------------
__global__ void finalize_stats_kernel(const double* __restrict__ slots, int C, double cnt,
    const float* __restrict__ g, const float* __restrict__ bta, float* __restrict__ scsh)
{
  int o = threadIdx.x;
  if (o < C) {
    double s = 0.0, ss = 0.0;
    for (int slot = 0; slot < 256; ++slot) { s += slots[slot * 2 * C + o]; ss += slots[slot * 2 * C + C + o]; }
    double mu = s / cnt;
    double var = ss / cnt - mu * mu;
    double rs = 1.0 / sqrt(var + 1e-5);
    float sc = (float)rs * g[o];
    float sh = bta[o] - (float)mu * sc;
    scsh[o] = sc;
    scsh[C + o] = sh;
  }
}

// ---------------- f1 = lrelu(affine(h1max)) ----------------
__global__ void apply_f1_kernel(const float* __restrict__ h1max, const float* __restrict__ scsh,
                                float* __restrict__ f1)
{
  int i = blockIdx.x * 256 + threadIdx.x;
  int o = i & 31;
  f1[i] = lrelu(h1max[i] * scsh[o] + scsh[32 + o]);
}

// ---------------- K6: h2 pre-act stats only ----------------
__global__ __launch_bounds__(256) void h2_stats_kernel(
    const float* __restrict__ f1, const int* __restrict__ idx_fps, const float* __restrict__ W2,
    double* __restrict__ slotsH2)
{
  __shared__ float sW2t[4096];   // [c][o]
  __shared__ float nbr[1024];
  __shared__ float ctr[32];
  __shared__ int nid[32];
  __shared__ float bsum[64], bss[64];
  int tid = threadIdx.x;
  int r = blockIdx.x, b = r >> 12;
  const float* f1b = f1 + (size_t)b * NPTS * 32;
  for (int i = tid; i < 4096; i += 256) { int o = i >> 6, c = i & 63; sW2t[c * 64 + o] = W2[i]; }
  if (tid < 32) { ctr[tid] = f1[(size_t)r * 32 + tid]; nid[tid] = idx_fps[r * 32 + tid]; }
  if (tid < 64) { bsum[tid] = 0.f; bss[tid] = 0.f; }
  __syncthreads();
  for (int t = tid; t < 1024; t += 256) { int k = t >> 5, c = t & 31; nbr[t] = f1b[(size_t)nid[k] * 32 + c]; }
  __syncthreads();
  float ls = 0.f, lss = 0.f;
  for (int m = tid; m < 2048; m += 256) {
    int k = m >> 6, o = m & 63;
    float acc = 0.f;
    #pragma unroll
    for (int c = 0; c < 32; ++c) acc += (nbr[k * 32 + c] - ctr[c]) * sW2t[c * 64 + o];
    #pragma unroll
    for (int c = 0; c < 32; ++c) acc += ctr[c] * sW2t[(32 + c) * 64 + o];
    ls += acc; lss += acc * acc;
  }
  atomicAdd(&bsum[tid & 63], ls);
  atomicAdd(&bss[tid & 63], lss);
  __syncthreads();
  if (tid < 64) {
    int slot = r & 255;
    atomicAdd(&slotsH2[slot * 128 + tid], (double)bsum[tid]);
    atomicAdd(&slotsH2[slot * 128 + 64 + tid], (double)bss[tid]);
  }
}

// ---------------- K8: recompute h2, BN+lrelu, h3 pre-act stats + channel max ----------------
__global__ __launch_bounds__(256) void h3_kernel(
    const float* __restrict__ f1, const int* __restrict__ idx_fps,
    const float* __restrict__ W2, const float* __restrict__ W3, const float* __restrict__ scsh2,
    double* __restrict__ slotsH3, float* __restrict__ h3max)
{
  __shared__ float sW2t[4096];
  __shared__ float sW3t[4096];
  __shared__ float nbr[1024];
  __shared__ float ctr[32];
  __shared__ int nid[32];
  __shared__ float h2post[2048];
  __shared__ float h3buf[2048];
  __shared__ float ssc[64], ssh[64];
  __shared__ float bsum[64], bss[64];
  int tid = threadIdx.x;
  int r = blockIdx.x, b = r >> 12;
  const float* f1b = f1 + (size_t)b * NPTS * 32;
  for (int i = tid; i < 4096; i += 256) {
    int o = i >> 6, c = i & 63;
    sW2t[c * 64 + o] = W2[i];
    sW3t[c * 64 + o] = W3[i];
  }
  if (tid < 32) { ctr[tid] = f1[(size_t)r * 32 + tid]; nid[tid] = idx_fps[r * 32 + tid]; }
  if (tid < 64) { bsum[tid] = 0.f; bss[tid] = 0.f; ssc[tid] = scsh2[tid]; ssh[tid] = scsh2[64 + tid]; }
  __syncthreads();
  for (int t = tid; t < 1024; t += 256) { int k = t >> 5, c = t & 31; nbr[t] = f1b[(size_t)nid[k] * 32 + c]; }
  __syncthreads();
  for (int m = tid; m < 2048; m += 256) {
    int k = m >> 6, o = m & 63;
    float acc = 0.f;
    #pragma unroll
    for (int c = 0; c < 32; ++c) acc += (nbr[k * 32 + c] - ctr[c]) * sW2t[c * 64 + o];
    #pragma unroll
    for (int c = 0; c < 32; ++c) acc += ctr[c] * sW2t[(32 + c) * 64 + o];
    h2post[m] = lrelu(acc * ssc[o] + ssh[o]);
  }
  __syncthreads();
  float ls = 0.f, lss = 0.f;
  for (int m = tid; m < 2048; m += 256) {
    int k = m >> 6, o = m & 63;
    float acc = 0.f;
    #pragma unroll
    for (int h = 0; h < 64; ++h) acc += h2post[k * 64 + h] * sW3t[h * 64 + o];
    h3buf[m] = acc;
    ls += acc; lss += acc * acc;
  }
  atomicAdd(&bsum[tid & 63], ls);
  atomicAdd(&bss[tid & 63], lss);
  __syncthreads();
  if (tid < 64) {
    float mx = h3buf[tid];
    #pragma unroll
    for (int k = 1; k < 32; ++k) mx = fmaxf(mx, h3buf[k * 64 + tid]);
    h3max[(size_t)r * 64 + tid] = mx;
    int slot = r & 255;
    atomicAdd(&slotsH3[slot * 128 + tid], (double)bsum[tid]);
    atomicAdd(&slotsH3[slot * 128 + 64 + tid], (double)bss[tid]);
  }
}

// ---------------- K10: out = lrelu(affine(h3max)) ----------------
__global__ void out_kernel(const float* __restrict__ h3max, const float* __restrict__ scsh3,
                           float* __restrict__ out)
{
  int i = blockIdx.x * 256 + threadIdx.x;
  int o = i & 63;
  out[i] = lrelu(h3max[i] * scsh3[o] + scsh3[64 + o]);
}

extern "C" void kernel_launch(void* const* d_in, const int* in_sizes, int n_in,
                              void* d_out, int out_size, void* d_ws, size_t ws_size,
                              hipStream_t stream) {
  (void)in_sizes; (void)n_in; (void)out_size; (void)ws_size;
  const float* x   = (const float*)d_in[0];
  const float* pos = (const float*)d_in[1];
  const float* W1  = (const float*)d_in[2];
  const float* g1  = (const float*)d_in[3];
  const float* b1  = (const float*)d_in[4];
  const float* W2  = (const float*)d_in[5];
  const float* g2  = (const float*)d_in[6];
  const float* b2  = (const float*)d_in[7];
  const float* W3  = (const float*)d_in[8];
  const float* g3  = (const float*)d_in[9];
  const float* b3  = (const float*)d_in[10];

  float* out      = (float*)d_out;             // (4,4096,64) f32
  float* out_idx1 = out + 1048576;             // (4,4096,14) written as float(idx)

  char* ws = (char*)d_ws;
  double* slotsH1 = (double*)(ws + 0);         // 256 x 64 double
  double* slotsH2 = (double*)(ws + 131072);    // 256 x 128 double
  double* slotsH3 = (double*)(ws + 393216);    // 256 x 128 double
  float*  scsh1   = (float*)(ws + 655360);     // 64 f
  float*  scsh2   = (float*)(ws + 655616);     // 128 f
  float*  scsh3   = (float*)(ws + 656128);     // 128 f
  int*    idx_l   = (int*)(ws + 1048576);      // 16384 x 128
  int*    idx_fps = (int*)(ws + 9437184);      // 16384 x 32
  int*    idx1_i  = (int*)(ws + 11534336);     // 16384 x 14
  float*  h1max   = (float*)(ws + 12451840);   // 16384 x 32
  float*  f1      = (float*)(ws + 14548992);   // 16384 x 32
  float*  h3max   = (float*)(ws + 16646144);   // 16384 x 64

  hipMemsetAsync(d_ws, 0, 656640, stream);     // zero stat accumulators

  knn_pos_kernel <<<dim3(16384), dim3(256), 0, stream>>>(pos, idx_l, idx1_i, out_idx1);
  knn_feat_kernel<<<dim3(4096),  dim3(512), 0, stream>>>(x, idx1_i, out_idx1);
  fps_kernel     <<<dim3(4096),  dim3(256), 0, stream>>>(pos, idx_l, idx_fps);
  h1_kernel      <<<dim3(16384), dim3(256), 0, stream>>>(x, idx1_i, W1, slotsH1, h1max);
  finalize_stats_kernel<<<dim3(1), dim3(64), 0, stream>>>(slotsH1, 32, 229376.0, g1, b1, scsh1);
  apply_f1_kernel<<<dim3(2048),  dim3(256), 0, stream>>>(h1max, scsh1, f1);
  h2_stats_kernel<<<dim3(16384), dim3(256), 0, stream>>>(f1, idx_fps, W2, slotsH2);
  finalize_stats_kernel<<<dim3(1), dim3(64), 0, stream>>>(slotsH2, 64, 524288.0, g2, b2, scsh2);
  h3_kernel      <<<dim3(16384), dim3(256), 0, stream>>>(f1, idx_fps, W2, W3, scsh2, slotsH3, h3max);
  finalize_stats_kernel<<<dim3(1), dim3(64), 0, stream>>>(slotsH3, 64, 524288.0, g3, b3, scsh3);
  out_kernel     <<<dim3(4096),  dim3(256), 0, stream>>>(h3max, scsh3, out);
}

// Round 3
// 1434.685 us; speedup vs baseline: 2.1407x; 1.2665x over previous
//
#include <hip/hip_runtime.h>

#define NPTS 4096
#define BNROWS 16384

__device__ __forceinline__ float lrelu(float h) { return h > 0.f ? h : 0.2f * h; }

// ================= K1: pos 128-NN (sorted) + idx_pos ==================
// 8 waves/block, one row per wave. Register keys, u16-quantized ballot
// binary-search threshold (>=129 guaranteed below), fp64 rerank of <=512
// candidates, wave-private bitonic-512.
__global__ __launch_bounds__(512) void knn_pos_kernel(
    const float* __restrict__ pos, int* __restrict__ idx_l,
    int* __restrict__ idx1_i, float* __restrict__ idx1_f)
{
  __shared__ unsigned long long cKey[8][512];
  __shared__ int cIdx[8][512];
  __shared__ unsigned int cCnt[8];
  int tid = threadIdx.x;
  int w = tid >> 6, lane = tid & 63;
  int r = blockIdx.x * 8 + w;
  int b = r >> 12, n = r & 4095;
  const float* pb = pos + (size_t)b * NPTS * 3;
  float cx = pb[n*3+0], cy = pb[n*3+1], cz = pb[n*3+2];
  if (lane == 0) cCnt[w] = 0u;

  unsigned int qp[32];
  int m1 = 65536, m2 = 65536, m3 = 65536;   // 3 smallest quantized keys (this lane)
  #pragma unroll
  for (int t = 0; t < 32; ++t) {
    unsigned int wq = 0u;
    #pragma unroll
    for (int h = 0; h < 2; ++h) {
      int j = (2*t + h) * 64 + lane;
      float dx = cx - pb[j*3+0], dy = cy - pb[j*3+1], dz = cz - pb[j*3+2];
      float d2 = dx*dx + dy*dy + dz*dz;
      int q = (int)(d2 * 1000.0f);
      q = q < 0 ? 0 : (q > 65535 ? 65535 : q);
      wq |= ((unsigned int)q) << (16*h);
      int nm1 = min(m1, q);
      int nm2 = min(m2, max(m1, q));
      int nm3 = min(m3, max(m2, q));
      m1 = nm1; m2 = nm2; m3 = nm3;
    }
    qp[t] = wq;
  }
  // threshold: smallest qt with >=43 lanes having 3rd-min <= qt  => >=129 pts <= qt
  int lo = 0, hi = 65535;
  #pragma unroll
  for (int it = 0; it < 16; ++it) {
    int mid = (lo + hi) >> 1;
    int cnt = __popcll(__ballot(m3 <= mid));
    if (cnt >= 43) hi = mid; else lo = mid + 1;
  }
  unsigned int qt = (unsigned int)lo + 2u;   // +2 bucket slack (fp32 vs fp64 ordering)

  // candidate compaction
  #pragma unroll
  for (int t = 0; t < 32; ++t) {
    unsigned int wq = qp[t];
    unsigned int q0 = wq & 0xffffu, q1 = wq >> 16;
    if (q0 <= qt) { unsigned int p = atomicAdd(&cCnt[w], 1u); if (p < 512u) cIdx[w][p] = (2*t)*64 + lane; }
    if (q1 <= qt) { unsigned int p = atomicAdd(&cCnt[w], 1u); if (p < 512u) cIdx[w][p] = (2*t+1)*64 + lane; }
  }
  __syncthreads();
  unsigned int nc = cCnt[w]; if (nc > 512u) nc = 512u;

  // exact fp64 rerank + pad
  double cxd = (double)cx, cyd = (double)cy, czd = (double)cz;
  #pragma unroll
  for (int t = 0; t < 8; ++t) {
    int c = lane + 64*t;
    unsigned long long kk = ~0ull; int id = 0x7fffffff;
    if (c < (int)nc) {
      id = cIdx[w][c];
      double dx = cxd - (double)pb[id*3+0];
      double dy = cyd - (double)pb[id*3+1];
      double dz = czd - (double)pb[id*3+2];
      kk = (unsigned long long)__double_as_longlong(dx*dx + dy*dy + dz*dz);
    }
    cKey[w][c] = kk; cIdx[w][c] = id;
  }
  __syncthreads();

  // bitonic-512 on (key,idx), ascending, idx tie-break
  for (int k = 2; k <= 512; k <<= 1) {
    for (int j = k >> 1; j > 0; j >>= 1) {
      #pragma unroll
      for (int t = 0; t < 8; ++t) {
        int i = lane + 64*t;
        int ixj = i ^ j;
        if (ixj > i) {
          unsigned long long ka = cKey[w][i], kb = cKey[w][ixj];
          int ia = cIdx[w][i], ib = cIdx[w][ixj];
          bool agtb = (ka > kb) || (ka == kb && ia > ib);
          bool up = ((i & k) == 0);
          if (agtb == up) { cKey[w][i] = kb; cKey[w][ixj] = ka; cIdx[w][i] = ib; cIdx[w][ixj] = ia; }
        }
      }
      __syncthreads();
    }
  }
  idx_l[(size_t)r * 128 + lane]      = cIdx[w][lane];
  idx_l[(size_t)r * 128 + lane + 64] = cIdx[w][lane + 64];
  if (lane < 6) {
    int v = cIdx[w][1 + lane];
    idx1_i[r * 14 + 8 + lane] = v;
    idx1_f[r * 14 + 8 + lane] = (float)v;
  }
}

// ================= K2: feature 8-NN (excl self) ==================
// 8 rows per 512-thread block; Gram-form fp32 keys in registers; per-thread
// min per row -> per-row ballot binary-search threshold (>=10 guaranteed);
// candidate compaction (<=~90); fp64 rerank + 9 wave min-extractions.
__global__ __launch_bounds__(512) void knn_feat_kernel(
    const float* __restrict__ x, int* __restrict__ idx1_i, float* __restrict__ idx1_f)
{
  __shared__ float ctrf[8][16];
  __shared__ float4 cm2[8][5];           // [r][0..3]=-2*ctr (16f), [4].x=|ctr|^2
  __shared__ unsigned short lmin[8][512];
  __shared__ int cand[8][192];
  __shared__ unsigned int cCnt[8];
  __shared__ unsigned short qtS[8];
  int tid = threadIdx.x;
  int rbase = blockIdx.x * 8;
  int b = rbase >> 12;
  const float* xb = x + (size_t)b * NPTS * 16;

  if (tid < 128) {
    int rr = tid >> 4, c = tid & 15;
    float v = xb[(size_t)((rbase + rr) & 4095) * 16 + c];
    ctrf[rr][c] = v;
    ((float*)&cm2[rr][0])[c] = -2.0f * v;
  }
  if (tid < 8) cCnt[tid] = 0u;
  __syncthreads();
  if (tid < 8) {
    float s = 0.f;
    for (int c = 0; c < 16; ++c) { float v = ctrf[tid][c]; s += v * v; }
    cm2[tid][4].x = s;
  }
  __syncthreads();

  unsigned int qp[8][4];
  int minq[8];
  #pragma unroll
  for (int r = 0; r < 8; ++r) minq[r] = 65536;

  #pragma unroll
  for (int pp = 0; pp < 4; ++pp) {
    int j0 = tid + 512 * (2*pp);
    int j1 = j0 + 512;
    const float4* xj0 = (const float4*)(xb + (size_t)j0 * 16);
    const float4* xj1 = (const float4*)(xb + (size_t)j1 * 16);
    float4 a0 = xj0[0], a1 = xj0[1], a2 = xj0[2], a3 = xj0[3];
    float4 b0 = xj1[0], b1 = xj1[1], b2 = xj1[2], b3 = xj1[3];
    float va[16] = {a0.x,a0.y,a0.z,a0.w, a1.x,a1.y,a1.z,a1.w,
                    a2.x,a2.y,a2.z,a2.w, a3.x,a3.y,a3.z,a3.w};
    float vb[16] = {b0.x,b0.y,b0.z,b0.w, b1.x,b1.y,b1.z,b1.w,
                    b2.x,b2.y,b2.z,b2.w, b3.x,b3.y,b3.z,b3.w};
    float pna = 0.f, pnb = 0.f;
    #pragma unroll
    for (int c = 0; c < 16; ++c) { pna = fmaf(va[c], va[c], pna); pnb = fmaf(vb[c], vb[c], pnb); }
    #pragma unroll
    for (int r = 0; r < 8; ++r) {
      float4 m0 = cm2[r][0], m1 = cm2[r][1], m2 = cm2[r][2], m3 = cm2[r][3];
      float c2 = cm2[r][4].x;
      float wm[16] = {m0.x,m0.y,m0.z,m0.w, m1.x,m1.y,m1.z,m1.w,
                      m2.x,m2.y,m2.z,m2.w, m3.x,m3.y,m3.z,m3.w};
      float aa = pna + c2, ab = pnb + c2;
      #pragma unroll
      for (int c = 0; c < 16; ++c) { aa = fmaf(wm[c], va[c], aa); ab = fmaf(wm[c], vb[c], ab); }
      int qa = (int)(aa * 400.0f); qa = qa < 0 ? 0 : (qa > 65535 ? 65535 : qa);
      int qb = (int)(ab * 400.0f); qb = qb < 0 ? 0 : (qb > 65535 ? 65535 : qb);
      qp[r][pp] = (unsigned int)qa | ((unsigned int)qb << 16);
      minq[r] = min(minq[r], min(qa, qb));
    }
  }
  #pragma unroll
  for (int r = 0; r < 8; ++r) lmin[r][tid] = (unsigned short)minq[r];
  __syncthreads();

  // per-wave: threshold for row w (10th smallest of 512 thread-minima)
  int w = tid >> 6, lane = tid & 63;
  {
    unsigned short lv[8];
    #pragma unroll
    for (int t = 0; t < 8; ++t) lv[t] = lmin[w][lane + 64*t];
    int lo = 0, hi = 65535;
    #pragma unroll
    for (int it = 0; it < 16; ++it) {
      int mid = (lo + hi) >> 1;
      int cnt = 0;
      #pragma unroll
      for (int t = 0; t < 8; ++t) cnt += __popcll(__ballot((int)lv[t] <= mid));
      if (cnt >= 10) hi = mid; else lo = mid + 1;
    }
    if (lane == 0) qtS[w] = (unsigned short)min(lo + 2, 65535);
  }
  __syncthreads();

  // candidate compaction (per thread, all 8 rows)
  {
    unsigned int qts[8];
    #pragma unroll
    for (int r = 0; r < 8; ++r) qts[r] = qtS[r];
    #pragma unroll
    for (int r = 0; r < 8; ++r) {
      #pragma unroll
      for (int pp = 0; pp < 4; ++pp) {
        unsigned int wq = qp[r][pp];
        unsigned int q0 = wq & 0xffffu, q1 = wq >> 16;
        if (q0 <= qts[r]) { unsigned int p = atomicAdd(&cCnt[r], 1u); if (p < 192u) cand[r][p] = tid + 512*(2*pp); }
        if (q1 <= qts[r]) { unsigned int p = atomicAdd(&cCnt[r], 1u); if (p < 192u) cand[r][p] = tid + 512*(2*pp+1); }
      }
    }
  }
  __syncthreads();

  // per-wave: fp64 rerank + 9 sorted min-extractions (rank0 = self, dropped)
  {
    int nc = (int)cCnt[w]; if (nc > 192) nc = 192;
    double key[3]; int kid[3];
    #pragma unroll
    for (int s = 0; s < 3; ++s) {
      int c = lane + 64*s;
      if (c < nc) {
        int id = cand[w][c];
        const float4* xp = (const float4*)(xb + (size_t)id * 16);
        float4 q0 = xp[0], q1 = xp[1], q2 = xp[2], q3 = xp[3];
        float xv[16] = {q0.x,q0.y,q0.z,q0.w, q1.x,q1.y,q1.z,q1.w,
                        q2.x,q2.y,q2.z,q2.w, q3.x,q3.y,q3.z,q3.w};
        double acc = 0.0;
        #pragma unroll
        for (int c2 = 0; c2 < 16; ++c2) { double d = (double)ctrf[w][c2] - (double)xv[c2]; acc += d * d; }
        key[s] = acc; kid[s] = id;
      } else { key[s] = 1e300; kid[s] = 0x7fffffff; }
    }
    int row = rbase + w;
    for (int it = 0; it < 9; ++it) {
      double bk = key[0]; int bi = kid[0], bs = 0;
      if (key[1] < bk || (key[1] == bk && kid[1] < bi)) { bk = key[1]; bi = kid[1]; bs = 1; }
      if (key[2] < bk || (key[2] == bk && kid[2] < bi)) { bk = key[2]; bi = kid[2]; bs = 2; }
      double rk = bk; int ri = bi;
      #pragma unroll
      for (int off = 32; off > 0; off >>= 1) {
        double ok = __shfl_xor(rk, off, 64);
        int oi = __shfl_xor(ri, off, 64);
        if (ok < rk || (ok == rk && oi < ri)) { rk = ok; ri = oi; }
      }
      if (it > 0 && lane == 0) {
        idx1_i[row * 14 + it - 1] = ri;
        idx1_f[row * 14 + it - 1] = (float)ri;
      }
      if (bi == ri) key[bs] = 1e300;
    }
  }
}

// ================= K3: FPS (replicates reference's batch-0 gather) =============
__global__ __launch_bounds__(256) void fps_kernel(
    const float* __restrict__ pos, const int* __restrict__ idx_l, int* __restrict__ idx_fps)
{
  int wave = threadIdx.x >> 6, lane = threadIdx.x & 63;
  int r = blockIdx.x * 4 + wave;
  const int* il = idx_l + (size_t)r * 128;
  int gi0 = il[lane], gi1 = il[lane + 64];
  double x0 = (double)pos[gi0*3+0], y0 = (double)pos[gi0*3+1], z0 = (double)pos[gi0*3+2];
  double x1 = (double)pos[gi1*3+0], y1 = (double)pos[gi1*3+1], z1 = (double)pos[gi1*3+2];
  double d0 = 1e10, d1 = 1e10;
  int far = 0;
  int* outp = idx_fps + (size_t)r * 32;
  for (int i = 0; i < 32; ++i) {
    int ownerLane = far & 63;
    int sel = far >> 6;
    int gsel = sel ? gi1 : gi0;
    int gout = __shfl(gsel, ownerLane, 64);
    if (lane == 0) outp[i] = gout;
    double cx = __shfl(sel ? x1 : x0, ownerLane, 64);
    double cy = __shfl(sel ? y1 : y0, ownerLane, 64);
    double cz = __shfl(sel ? z1 : z0, ownerLane, 64);
    double t0 = (x0-cx)*(x0-cx) + (y0-cy)*(y0-cy) + (z0-cz)*(z0-cz);
    double t1 = (x1-cx)*(x1-cx) + (y1-cy)*(y1-cy) + (z1-cz)*(z1-cz);
    d0 = fmin(d0, t0); d1 = fmin(d1, t1);
    double v; int p;
    if (d1 > d0) { v = d1; p = lane + 64; } else { v = d0; p = lane; }
    for (int off = 32; off > 0; off >>= 1) {
      double ov = __shfl_xor(v, off, 64);
      int op = __shfl_xor(p, off, 64);
      if (ov > v || (ov == v && op < p)) { v = ov; p = op; }
    }
    far = p;
  }
}

// ================= K4: h1 pre-act stats + per-(b,n) channel max =============
__global__ __launch_bounds__(256) void h1_kernel(
    const float* __restrict__ x, const int* __restrict__ idx1_i, const float* __restrict__ W1,
    double* __restrict__ slotsH1, float* __restrict__ h1max)
{
  __shared__ float sW1t[1024];   // [c][o]
  __shared__ float nbr[224];
  __shared__ float ctr[16];
  __shared__ float hbuf[448];
  __shared__ float bsum[32], bss[32];
  int tid = threadIdx.x;
  int r = blockIdx.x, b = r >> 12;
  const float* xb = x + (size_t)b * NPTS * 16;
  for (int i = tid; i < 1024; i += 256) { int o = i >> 5, c = i & 31; sW1t[c * 32 + o] = W1[i]; }
  if (tid < 16) ctr[tid] = xb[(size_t)(r & 4095) * 16 + tid];
  if (tid < 32) { bsum[tid] = 0.f; bss[tid] = 0.f; }
  if (tid < 224) { int k = tid >> 4, c = tid & 15; int j = idx1_i[r * 14 + k]; nbr[tid] = xb[(size_t)j * 16 + c]; }
  __syncthreads();
  float ls = 0.f, lss = 0.f;
  for (int m = tid; m < 448; m += 256) {
    int k = m >> 5, o = m & 31;
    float acc = 0.f;
    #pragma unroll
    for (int c = 0; c < 16; ++c) acc += (nbr[k * 16 + c] - ctr[c]) * sW1t[c * 32 + o];
    #pragma unroll
    for (int c = 0; c < 16; ++c) acc += ctr[c] * sW1t[(16 + c) * 32 + o];
    hbuf[m] = acc;
    ls += acc; lss += acc * acc;
  }
  atomicAdd(&bsum[tid & 31], ls);
  atomicAdd(&bss[tid & 31], lss);
  __syncthreads();
  if (tid < 32) {
    float mx = hbuf[tid];
    #pragma unroll
    for (int k = 1; k < 14; ++k) mx = fmaxf(mx, hbuf[k * 32 + tid]);
    h1max[(size_t)r * 32 + tid] = mx;
    int slot = r & 255;
    atomicAdd(&slotsH1[slot * 64 + tid], (double)bsum[tid]);
    atomicAdd(&slotsH1[slot * 64 + 32 + tid], (double)bss[tid]);
  }
}

// ---------------- stats finalize: scsh = [sc(C), sh(C)] ----------------
__global__ void finalize_stats_kernel(const double* __restrict__ slots, int C, double cnt,
    const float* __restrict__ g, const float* __restrict__ bta, float* __restrict__ scsh)
{
  int o = threadIdx.x;
  if (o < C) {
    double s = 0.0, ss = 0.0;
    for (int slot = 0; slot < 256; ++slot) { s += slots[slot * 2 * C + o]; ss += slots[slot * 2 * C + C + o]; }
    double mu = s / cnt;
    double var = ss / cnt - mu * mu;
    double rs = 1.0 / sqrt(var + 1e-5);
    float sc = (float)rs * g[o];
    float sh = bta[o] - (float)mu * sc;
    scsh[o] = sc;
    scsh[C + o] = sh;
  }
}

// ---------------- f1 = lrelu(affine(h1max)) ----------------
__global__ void apply_f1_kernel(const float* __restrict__ h1max, const float* __restrict__ scsh,
                                float* __restrict__ f1)
{
  int i = blockIdx.x * 256 + threadIdx.x;
  int o = i & 31;
  f1[i] = lrelu(h1max[i] * scsh[o] + scsh[32 + o]);
}

// ---------------- K6: h2 pre-act stats only ----------------
__global__ __launch_bounds__(256) void h2_stats_kernel(
    const float* __restrict__ f1, const int* __restrict__ idx_fps, const float* __restrict__ W2,
    double* __restrict__ slotsH2)
{
  __shared__ float sW2t[4096];   // [c][o]
  __shared__ float nbr[1024];
  __shared__ float ctr[32];
  __shared__ int nid[32];
  __shared__ float bsum[64], bss[64];
  int tid = threadIdx.x;
  int r = blockIdx.x, b = r >> 12;
  const float* f1b = f1 + (size_t)b * NPTS * 32;
  for (int i = tid; i < 4096; i += 256) { int o = i >> 6, c = i & 63; sW2t[c * 64 + o] = W2[i]; }
  if (tid < 32) { ctr[tid] = f1[(size_t)r * 32 + tid]; nid[tid] = idx_fps[r * 32 + tid]; }
  if (tid < 64) { bsum[tid] = 0.f; bss[tid] = 0.f; }
  __syncthreads();
  for (int t = tid; t < 1024; t += 256) { int k = t >> 5, c = t & 31; nbr[t] = f1b[(size_t)nid[k] * 32 + c]; }
  __syncthreads();
  float ls = 0.f, lss = 0.f;
  for (int m = tid; m < 2048; m += 256) {
    int k = m >> 6, o = m & 63;
    float acc = 0.f;
    #pragma unroll
    for (int c = 0; c < 32; ++c) acc += (nbr[k * 32 + c] - ctr[c]) * sW2t[c * 64 + o];
    #pragma unroll
    for (int c = 0; c < 32; ++c) acc += ctr[c] * sW2t[(32 + c) * 64 + o];
    ls += acc; lss += acc * acc;
  }
  atomicAdd(&bsum[tid & 63], ls);
  atomicAdd(&bss[tid & 63], lss);
  __syncthreads();
  if (tid < 64) {
    int slot = r & 255;
    atomicAdd(&slotsH2[slot * 128 + tid], (double)bsum[tid]);
    atomicAdd(&slotsH2[slot * 128 + 64 + tid], (double)bss[tid]);
  }
}

// ------- K8: recompute h2, BN+lrelu, h3 pre-act stats + channel max -------
__global__ __launch_bounds__(256) void h3_kernel(
    const float* __restrict__ f1, const int* __restrict__ idx_fps,
    const float* __restrict__ W2, const float* __restrict__ W3, const float* __restrict__ scsh2,
    double* __restrict__ slotsH3, float* __restrict__ h3max)
{
  __shared__ float sW2t[4096];
  __shared__ float sW3t[4096];
  __shared__ float nbr[1024];
  __shared__ float ctr[32];
  __shared__ int nid[32];
  __shared__ float h2post[2048];
  __shared__ float h3buf[2048];
  __shared__ float ssc[64], ssh[64];
  __shared__ float bsum[64], bss[64];
  int tid = threadIdx.x;
  int r = blockIdx.x, b = r >> 12;
  const float* f1b = f1 + (size_t)b * NPTS * 32;
  for (int i = tid; i < 4096; i += 256) {
    int o = i >> 6, c = i & 63;
    sW2t[c * 64 + o] = W2[i];
    sW3t[c * 64 + o] = W3[i];
  }
  if (tid < 32) { ctr[tid] = f1[(size_t)r * 32 + tid]; nid[tid] = idx_fps[r * 32 + tid]; }
  if (tid < 64) { bsum[tid] = 0.f; bss[tid] = 0.f; ssc[tid] = scsh2[tid]; ssh[tid] = scsh2[64 + tid]; }
  __syncthreads();
  for (int t = tid; t < 1024; t += 256) { int k = t >> 5, c = t & 31; nbr[t] = f1b[(size_t)nid[k] * 32 + c]; }
  __syncthreads();
  for (int m = tid; m < 2048; m += 256) {
    int k = m >> 6, o = m & 63;
    float acc = 0.f;
    #pragma unroll
    for (int c = 0; c < 32; ++c) acc += (nbr[k * 32 + c] - ctr[c]) * sW2t[c * 64 + o];
    #pragma unroll
    for (int c = 0; c < 32; ++c) acc += ctr[c] * sW2t[(32 + c) * 64 + o];
    h2post[m] = lrelu(acc * ssc[o] + ssh[o]);
  }
  __syncthreads();
  float ls = 0.f, lss = 0.f;
  for (int m = tid; m < 2048; m += 256) {
    int k = m >> 6, o = m & 63;
    float acc = 0.f;
    #pragma unroll
    for (int h = 0; h < 64; ++h) acc += h2post[k * 64 + h] * sW3t[h * 64 + o];
    h3buf[m] = acc;
    ls += acc; lss += acc * acc;
  }
  atomicAdd(&bsum[tid & 63], ls);
  atomicAdd(&bss[tid & 63], lss);
  __syncthreads();
  if (tid < 64) {
    float mx = h3buf[tid];
    #pragma unroll
    for (int k = 1; k < 32; ++k) mx = fmaxf(mx, h3buf[k * 64 + tid]);
    h3max[(size_t)r * 64 + tid] = mx;
    int slot = r & 255;
    atomicAdd(&slotsH3[slot * 128 + tid], (double)bsum[tid]);
    atomicAdd(&slotsH3[slot * 128 + 64 + tid], (double)bss[tid]);
  }
}

// ---------------- K10: out = lrelu(affine(h3max)) ----------------
__global__ void out_kernel(const float* __restrict__ h3max, const float* __restrict__ scsh3,
                           float* __restrict__ out)
{
  int i = blockIdx.x * 256 + threadIdx.x;
  int o = i & 63;
  out[i] = lrelu(h3max[i] * scsh3[o] + scsh3[64 + o]);
}

extern "C" void kernel_launch(void* const* d_in, const int* in_sizes, int n_in,
                              void* d_out, int out_size, void* d_ws, size_t ws_size,
                              hipStream_t stream) {
  (void)in_sizes; (void)n_in; (void)out_size; (void)ws_size;
  const float* x   = (const float*)d_in[0];
  const float* pos = (const float*)d_in[1];
  const float* W1  = (const float*)d_in[2];
  const float* g1  = (const float*)d_in[3];
  const float* b1  = (const float*)d_in[4];
  const float* W2  = (const float*)d_in[5];
  const float* g2  = (const float*)d_in[6];
  const float* b2  = (const float*)d_in[7];
  const float* W3  = (const float*)d_in[8];
  const float* g3  = (const float*)d_in[9];
  const float* b3  = (const float*)d_in[10];

  float* out      = (float*)d_out;             // (4,4096,64) f32
  float* out_idx1 = out + 1048576;             // (4,4096,14) written as float(idx)

  char* ws = (char*)d_ws;
  double* slotsH1 = (double*)(ws + 0);         // 256 x 64 double
  double* slotsH2 = (double*)(ws + 131072);    // 256 x 128 double
  double* slotsH3 = (double*)(ws + 393216);    // 256 x 128 double
  float*  scsh1   = (float*)(ws + 655360);     // 64 f
  float*  scsh2   = (float*)(ws + 655616);     // 128 f
  float*  scsh3   = (float*)(ws + 656128);     // 128 f
  int*    idx_l   = (int*)(ws + 1048576);      // 16384 x 128
  int*    idx_fps = (int*)(ws + 9437184);      // 16384 x 32
  int*    idx1_i  = (int*)(ws + 11534336);     // 16384 x 14
  float*  h1max   = (float*)(ws + 12451840);   // 16384 x 32
  float*  f1      = (float*)(ws + 14548992);   // 16384 x 32
  float*  h3max   = (float*)(ws + 16646144);   // 16384 x 64

  hipMemsetAsync(d_ws, 0, 656640, stream);     // zero stat accumulators

  knn_pos_kernel <<<dim3(2048),  dim3(512), 0, stream>>>(pos, idx_l, idx1_i, out_idx1);
  knn_feat_kernel<<<dim3(2048),  dim3(512), 0, stream>>>(x, idx1_i, out_idx1);
  fps_kernel     <<<dim3(4096),  dim3(256), 0, stream>>>(pos, idx_l, idx_fps);
  h1_kernel      <<<dim3(16384), dim3(256), 0, stream>>>(x, idx1_i, W1, slotsH1, h1max);
  finalize_stats_kernel<<<dim3(1), dim3(64), 0, stream>>>(slotsH1, 32, 229376.0, g1, b1, scsh1);
  apply_f1_kernel<<<dim3(2048),  dim3(256), 0, stream>>>(h1max, scsh1, f1);
  h2_stats_kernel<<<dim3(16384), dim3(256), 0, stream>>>(f1, idx_fps, W2, slotsH2);
  finalize_stats_kernel<<<dim3(1), dim3(64), 0, stream>>>(slotsH2, 64, 524288.0, g2, b2, scsh2);
  h3_kernel      <<<dim3(16384), dim3(256), 0, stream>>>(f1, idx_fps, W2, W3, scsh2, slotsH3, h3max);
  finalize_stats_kernel<<<dim3(1), dim3(64), 0, stream>>>(slotsH3, 64, 524288.0, g3, b3, scsh3);
  out_kernel     <<<dim3(4096),  dim3(256), 0, stream>>>(h3max, scsh3, out);
}

// Round 4
// 1419.896 us; speedup vs baseline: 2.1630x; 1.0104x over previous
//
#include <hip/hip_runtime.h>

#define NPTS 4096
#define BNROWS 16384

__device__ __forceinline__ float lrelu(float h) { return h > 0.f ? h : 0.2f * h; }

// ================= K1: pos 128-NN (sorted) + idx_pos ==================
__global__ __launch_bounds__(512) void knn_pos_kernel(
    const float* __restrict__ pos, int* __restrict__ idx_l,
    int* __restrict__ idx1_i, float* __restrict__ idx1_f)
{
  __shared__ unsigned long long cKey[8][512];
  __shared__ int cIdx[8][512];
  __shared__ unsigned int cCnt[8];
  int tid = threadIdx.x;
  int w = tid >> 6, lane = tid & 63;
  int r = blockIdx.x * 8 + w;
  int b = r >> 12, n = r & 4095;
  const float* pb = pos + (size_t)b * NPTS * 3;
  float cx = pb[n*3+0], cy = pb[n*3+1], cz = pb[n*3+2];
  if (lane == 0) cCnt[w] = 0u;

  unsigned int qp[32];
  int m1 = 65536, m2 = 65536, m3 = 65536;
  #pragma unroll
  for (int t = 0; t < 32; ++t) {
    unsigned int wq = 0u;
    #pragma unroll
    for (int h = 0; h < 2; ++h) {
      int j = (2*t + h) * 64 + lane;
      float dx = cx - pb[j*3+0], dy = cy - pb[j*3+1], dz = cz - pb[j*3+2];
      float d2 = dx*dx + dy*dy + dz*dz;
      int q = (int)(d2 * 1000.0f);
      q = q < 0 ? 0 : (q > 65535 ? 65535 : q);
      wq |= ((unsigned int)q) << (16*h);
      int nm1 = min(m1, q);
      int nm2 = min(m2, max(m1, q));
      int nm3 = min(m3, max(m2, q));
      m1 = nm1; m2 = nm2; m3 = nm3;
    }
    qp[t] = wq;
  }
  int lo = 0, hi = 65535;
  #pragma unroll
  for (int it = 0; it < 16; ++it) {
    int mid = (lo + hi) >> 1;
    int cnt = __popcll(__ballot(m3 <= mid));
    if (cnt >= 43) hi = mid; else lo = mid + 1;
  }
  unsigned int qt = (unsigned int)lo + 2u;

  #pragma unroll
  for (int t = 0; t < 32; ++t) {
    unsigned int wq = qp[t];
    unsigned int q0 = wq & 0xffffu, q1 = wq >> 16;
    if (q0 <= qt) { unsigned int p = atomicAdd(&cCnt[w], 1u); if (p < 512u) cIdx[w][p] = (2*t)*64 + lane; }
    if (q1 <= qt) { unsigned int p = atomicAdd(&cCnt[w], 1u); if (p < 512u) cIdx[w][p] = (2*t+1)*64 + lane; }
  }
  __syncthreads();
  unsigned int nc = cCnt[w]; if (nc > 512u) nc = 512u;

  double cxd = (double)cx, cyd = (double)cy, czd = (double)cz;
  #pragma unroll
  for (int t = 0; t < 8; ++t) {
    int c = lane + 64*t;
    unsigned long long kk = ~0ull; int id = 0x7fffffff;
    if (c < (int)nc) {
      id = cIdx[w][c];
      double dx = cxd - (double)pb[id*3+0];
      double dy = cyd - (double)pb[id*3+1];
      double dz = czd - (double)pb[id*3+2];
      kk = (unsigned long long)__double_as_longlong(dx*dx + dy*dy + dz*dz);
    }
    cKey[w][c] = kk; cIdx[w][c] = id;
  }
  __syncthreads();

  for (int k = 2; k <= 512; k <<= 1) {
    for (int j = k >> 1; j > 0; j >>= 1) {
      #pragma unroll
      for (int t = 0; t < 8; ++t) {
        int i = lane + 64*t;
        int ixj = i ^ j;
        if (ixj > i) {
          unsigned long long ka = cKey[w][i], kb = cKey[w][ixj];
          int ia = cIdx[w][i], ib = cIdx[w][ixj];
          bool agtb = (ka > kb) || (ka == kb && ia > ib);
          bool up = ((i & k) == 0);
          if (agtb == up) { cKey[w][i] = kb; cKey[w][ixj] = ka; cIdx[w][i] = ib; cIdx[w][ixj] = ia; }
        }
      }
      __syncthreads();
    }
  }
  idx_l[(size_t)r * 128 + lane]      = cIdx[w][lane];
  idx_l[(size_t)r * 128 + lane + 64] = cIdx[w][lane + 64];
  if (lane < 6) {
    int v = cIdx[w][1 + lane];
    idx1_i[r * 14 + 8 + lane] = v;
    idx1_f[r * 14 + 8 + lane] = (float)v;
  }
}

// ================= K2: feature 8-NN (excl self) ==================
__global__ __launch_bounds__(512) void knn_feat_kernel(
    const float* __restrict__ x, int* __restrict__ idx1_i, float* __restrict__ idx1_f)
{
  __shared__ float ctrf[8][16];
  __shared__ float4 cm2[8][5];
  __shared__ unsigned short lmin[8][512];
  __shared__ int cand[8][192];
  __shared__ unsigned int cCnt[8];
  __shared__ unsigned short qtS[8];
  int tid = threadIdx.x;
  int rbase = blockIdx.x * 8;
  int b = rbase >> 12;
  const float* xb = x + (size_t)b * NPTS * 16;

  if (tid < 128) {
    int rr = tid >> 4, c = tid & 15;
    float v = xb[(size_t)((rbase + rr) & 4095) * 16 + c];
    ctrf[rr][c] = v;
    ((float*)&cm2[rr][0])[c] = -2.0f * v;
  }
  if (tid < 8) cCnt[tid] = 0u;
  __syncthreads();
  if (tid < 8) {
    float s = 0.f;
    for (int c = 0; c < 16; ++c) { float v = ctrf[tid][c]; s += v * v; }
    cm2[tid][4].x = s;
  }
  __syncthreads();

  unsigned int qp[8][4];
  int minq[8];
  #pragma unroll
  for (int r = 0; r < 8; ++r) minq[r] = 65536;

  #pragma unroll
  for (int pp = 0; pp < 4; ++pp) {
    int j0 = tid + 512 * (2*pp);
    int j1 = j0 + 512;
    const float4* xj0 = (const float4*)(xb + (size_t)j0 * 16);
    const float4* xj1 = (const float4*)(xb + (size_t)j1 * 16);
    float4 a0 = xj0[0], a1 = xj0[1], a2 = xj0[2], a3 = xj0[3];
    float4 b0 = xj1[0], b1 = xj1[1], b2 = xj1[2], b3 = xj1[3];
    float va[16] = {a0.x,a0.y,a0.z,a0.w, a1.x,a1.y,a1.z,a1.w,
                    a2.x,a2.y,a2.z,a2.w, a3.x,a3.y,a3.z,a3.w};
    float vb[16] = {b0.x,b0.y,b0.z,b0.w, b1.x,b1.y,b1.z,b1.w,
                    b2.x,b2.y,b2.z,b2.w, b3.x,b3.y,b3.z,b3.w};
    float pna = 0.f, pnb = 0.f;
    #pragma unroll
    for (int c = 0; c < 16; ++c) { pna = fmaf(va[c], va[c], pna); pnb = fmaf(vb[c], vb[c], pnb); }
    #pragma unroll
    for (int r = 0; r < 8; ++r) {
      float4 m0 = cm2[r][0], m1 = cm2[r][1], m2 = cm2[r][2], m3 = cm2[r][3];
      float c2 = cm2[r][4].x;
      float wm[16] = {m0.x,m0.y,m0.z,m0.w, m1.x,m1.y,m1.z,m1.w,
                      m2.x,m2.y,m2.z,m2.w, m3.x,m3.y,m3.z,m3.w};
      float aa = pna + c2, ab = pnb + c2;
      #pragma unroll
      for (int c = 0; c < 16; ++c) { aa = fmaf(wm[c], va[c], aa); ab = fmaf(wm[c], vb[c], ab); }
      int qa = (int)(aa * 400.0f); qa = qa < 0 ? 0 : (qa > 65535 ? 65535 : qa);
      int qb = (int)(ab * 400.0f); qb = qb < 0 ? 0 : (qb > 65535 ? 65535 : qb);
      qp[r][pp] = (unsigned int)qa | ((unsigned int)qb << 16);
      minq[r] = min(minq[r], min(qa, qb));
    }
  }
  #pragma unroll
  for (int r = 0; r < 8; ++r) lmin[r][tid] = (unsigned short)minq[r];
  __syncthreads();

  int w = tid >> 6, lane = tid & 63;
  {
    unsigned short lv[8];
    #pragma unroll
    for (int t = 0; t < 8; ++t) lv[t] = lmin[w][lane + 64*t];
    int lo = 0, hi = 65535;
    #pragma unroll
    for (int it = 0; it < 16; ++it) {
      int mid = (lo + hi) >> 1;
      int cnt = 0;
      #pragma unroll
      for (int t = 0; t < 8; ++t) cnt += __popcll(__ballot((int)lv[t] <= mid));
      if (cnt >= 10) hi = mid; else lo = mid + 1;
    }
    if (lane == 0) qtS[w] = (unsigned short)min(lo + 2, 65535);
  }
  __syncthreads();

  {
    unsigned int qts[8];
    #pragma unroll
    for (int r = 0; r < 8; ++r) qts[r] = qtS[r];
    #pragma unroll
    for (int r = 0; r < 8; ++r) {
      #pragma unroll
      for (int pp = 0; pp < 4; ++pp) {
        unsigned int wq = qp[r][pp];
        unsigned int q0 = wq & 0xffffu, q1 = wq >> 16;
        if (q0 <= qts[r]) { unsigned int p = atomicAdd(&cCnt[r], 1u); if (p < 192u) cand[r][p] = tid + 512*(2*pp); }
        if (q1 <= qts[r]) { unsigned int p = atomicAdd(&cCnt[r], 1u); if (p < 192u) cand[r][p] = tid + 512*(2*pp+1); }
      }
    }
  }
  __syncthreads();

  {
    int nc = (int)cCnt[w]; if (nc > 192) nc = 192;
    double key[3]; int kid[3];
    #pragma unroll
    for (int s = 0; s < 3; ++s) {
      int c = lane + 64*s;
      if (c < nc) {
        int id = cand[w][c];
        const float4* xp = (const float4*)(xb + (size_t)id * 16);
        float4 q0 = xp[0], q1 = xp[1], q2 = xp[2], q3 = xp[3];
        float xv[16] = {q0.x,q0.y,q0.z,q0.w, q1.x,q1.y,q1.z,q1.w,
                        q2.x,q2.y,q2.z,q2.w, q3.x,q3.y,q3.z,q3.w};
        double acc = 0.0;
        #pragma unroll
        for (int c2 = 0; c2 < 16; ++c2) { double d = (double)ctrf[w][c2] - (double)xv[c2]; acc += d * d; }
        key[s] = acc; kid[s] = id;
      } else { key[s] = 1e300; kid[s] = 0x7fffffff; }
    }
    int row = rbase + w;
    for (int it = 0; it < 9; ++it) {
      double bk = key[0]; int bi = kid[0], bs = 0;
      if (key[1] < bk || (key[1] == bk && kid[1] < bi)) { bk = key[1]; bi = kid[1]; bs = 1; }
      if (key[2] < bk || (key[2] == bk && kid[2] < bi)) { bk = key[2]; bi = kid[2]; bs = 2; }
      double rk = bk; int ri = bi;
      #pragma unroll
      for (int off = 32; off > 0; off >>= 1) {
        double ok = __shfl_xor(rk, off, 64);
        int oi = __shfl_xor(ri, off, 64);
        if (ok < rk || (ok == rk && oi < ri)) { rk = ok; ri = oi; }
      }
      if (it > 0 && lane == 0) {
        idx1_i[row * 14 + it - 1] = ri;
        idx1_f[row * 14 + it - 1] = (float)ri;
      }
      if (bi == ri) key[bs] = 1e300;
    }
  }
}

// ================= K3: FPS (replicates reference's batch-0 gather) =============
__global__ __launch_bounds__(256) void fps_kernel(
    const float* __restrict__ pos, const int* __restrict__ idx_l, int* __restrict__ idx_fps)
{
  int wave = threadIdx.x >> 6, lane = threadIdx.x & 63;
  int r = blockIdx.x * 4 + wave;
  const int* il = idx_l + (size_t)r * 128;
  int gi0 = il[lane], gi1 = il[lane + 64];
  double x0 = (double)pos[gi0*3+0], y0 = (double)pos[gi0*3+1], z0 = (double)pos[gi0*3+2];
  double x1 = (double)pos[gi1*3+0], y1 = (double)pos[gi1*3+1], z1 = (double)pos[gi1*3+2];
  double d0 = 1e10, d1 = 1e10;
  int far = 0;
  int* outp = idx_fps + (size_t)r * 32;
  for (int i = 0; i < 32; ++i) {
    int ownerLane = far & 63;
    int sel = far >> 6;
    int gsel = sel ? gi1 : gi0;
    int gout = __shfl(gsel, ownerLane, 64);
    if (lane == 0) outp[i] = gout;
    double cx = __shfl(sel ? x1 : x0, ownerLane, 64);
    double cy = __shfl(sel ? y1 : y0, ownerLane, 64);
    double cz = __shfl(sel ? z1 : z0, ownerLane, 64);
    double t0 = (x0-cx)*(x0-cx) + (y0-cy)*(y0-cy) + (z0-cz)*(z0-cz);
    double t1 = (x1-cx)*(x1-cx) + (y1-cy)*(y1-cy) + (z1-cz)*(z1-cz);
    d0 = fmin(d0, t0); d1 = fmin(d1, t1);
    double v; int p;
    if (d1 > d0) { v = d1; p = lane + 64; } else { v = d0; p = lane; }
    for (int off = 32; off > 0; off >>= 1) {
      double ov = __shfl_xor(v, off, 64);
      int op = __shfl_xor(p, off, 64);
      if (ov > v || (ov == v && op < p)) { v = ov; p = op; }
    }
    far = p;
  }
}

// ================= K4: h1 — 32 rows/block, register weights =============
#define ROWS1 32
__global__ __launch_bounds__(256) void h1_kernel(
    const float* __restrict__ x, const int* __restrict__ idx1_i, const float* __restrict__ W1,
    double* __restrict__ slotsH1, float* __restrict__ h1max)
{
  __shared__ float e1lds[448];
  __shared__ float smax[256];
  __shared__ float sred[256], sred2[256];
  int tid = threadIdx.x;
  int o = tid & 31;          // output channel / staging channel
  int slot = tid >> 5;       // 0..7
  float4 w1r[8];
  const float4* w1p = (const float4*)(W1 + o * 32);
  #pragma unroll
  for (int j = 0; j < 8; ++j) w1r[j] = w1p[j];
  int cc = (o < 16) ? o : (o - 16);
  float ls = 0.f, lss = 0.f;
  int rbase = blockIdx.x * ROWS1;

  for (int row = 0; row < ROWS1; ++row) {
    int r = rbase + row;
    int broff = r & ~4095;
    float xc = x[(size_t)r * 16 + cc];
    // stage e1: element m -> k=m>>5, c=m&31 (c == o)
    {
      int k = slot;          // m = tid
      float v;
      if (o < 16) { int j = idx1_i[r * 14 + k]; v = x[(size_t)(broff + j) * 16 + o] - xc; }
      else v = xc;
      e1lds[k * 32 + o] = v;
      if (tid < 192) {       // m = tid + 256 -> k = slot + 8 (<= 13)
        int k2 = slot + 8;
        float v2;
        if (o < 16) { int j2 = idx1_i[r * 14 + k2]; v2 = x[(size_t)(broff + j2) * 16 + o] - xc; }
        else v2 = xc;
        e1lds[k2 * 32 + o] = v2;
      }
    }
    __syncthreads();
    // compute h1 pre-act
    float mymax;
    {
      const float4* ep = (const float4*)(e1lds + slot * 32);
      float acc = 0.f;
      #pragma unroll
      for (int j = 0; j < 8; ++j) {
        float4 e = ep[j];
        acc = fmaf(e.x, w1r[j].x, acc); acc = fmaf(e.y, w1r[j].y, acc);
        acc = fmaf(e.z, w1r[j].z, acc); acc = fmaf(e.w, w1r[j].w, acc);
      }
      ls += acc; lss += acc * acc;
      mymax = acc;
      if (tid < 192) {
        const float4* ep2 = (const float4*)(e1lds + (slot + 8) * 32);
        float acc2 = 0.f;
        #pragma unroll
        for (int j = 0; j < 8; ++j) {
          float4 e = ep2[j];
          acc2 = fmaf(e.x, w1r[j].x, acc2); acc2 = fmaf(e.y, w1r[j].y, acc2);
          acc2 = fmaf(e.z, w1r[j].z, acc2); acc2 = fmaf(e.w, w1r[j].w, acc2);
        }
        ls += acc2; lss += acc2 * acc2;
        mymax = fmaxf(mymax, acc2);
      }
    }
    smax[tid] = mymax;
    __syncthreads();
    if (tid < 32) {
      float m = smax[tid];
      #pragma unroll
      for (int s = 1; s < 8; ++s) m = fmaxf(m, smax[s * 32 + tid]);
      h1max[(size_t)r * 32 + tid] = m;
    }
  }
  sred[tid] = ls; sred2[tid] = lss;
  __syncthreads();
  if (tid < 32) {
    float s = 0.f, ss = 0.f;
    #pragma unroll
    for (int j = 0; j < 8; ++j) { s += sred[j * 32 + tid]; ss += sred2[j * 32 + tid]; }
    int slot2 = blockIdx.x & 255;
    atomicAdd(&slotsH1[slot2 * 64 + tid], (double)s);
    atomicAdd(&slotsH1[slot2 * 64 + 32 + tid], (double)ss);
  }
}

// ---------------- stats finalize: scsh = [sc(C), sh(C)] ----------------
__global__ void finalize_stats_kernel(const double* __restrict__ slots, int C, double cnt,
    const float* __restrict__ g, const float* __restrict__ bta, float* __restrict__ scsh)
{
  int o = threadIdx.x;
  if (o < C) {
    double s = 0.0, ss = 0.0;
    for (int slot = 0; slot < 256; ++slot) { s += slots[slot * 2 * C + o]; ss += slots[slot * 2 * C + C + o]; }
    double mu = s / cnt;
    double var = ss / cnt - mu * mu;
    double rs = 1.0 / sqrt(var + 1e-5);
    float sc = (float)rs * g[o];
    float sh = bta[o] - (float)mu * sc;
    scsh[o] = sc;
    scsh[C + o] = sh;
  }
}

// ================= K6: h2 pre-act stats — 16 rows/block, reg weights ==========
#define ROWS2 16
__global__ __launch_bounds__(256) void h2_stats_kernel(
    const float* __restrict__ h1max, const int* __restrict__ idx_fps,
    const float* __restrict__ W2, const float* __restrict__ scsh1,
    double* __restrict__ slotsH2)
{
  __shared__ float e2lds[2048];
  __shared__ float sred[256], sred2[256];
  int tid = threadIdx.x;
  int o = tid & 63, wv = tid >> 6;
  float4 w2r[16];
  const float4* w2p = (const float4*)(W2 + o * 64);
  #pragma unroll
  for (int j = 0; j < 16; ++j) w2r[j] = w2p[j];
  int cc = (o < 32) ? o : (o - 32);
  float sc1c = scsh1[cc], sh1c = scsh1[32 + cc];
  float ls = 0.f, lss = 0.f;
  int rbase = blockIdx.x * ROWS2;

  for (int row = 0; row < ROWS2; ++row) {
    int r = rbase + row;
    int broff = r & ~4095;
    float fctr = lrelu(h1max[(size_t)r * 32 + cc] * sc1c + sh1c);
    #pragma unroll
    for (int i = 0; i < 8; ++i) {
      int k = wv + 4 * i;
      float v;
      if (o < 32) {
        int nid = idx_fps[r * 32 + k];
        v = lrelu(h1max[(size_t)(broff + nid) * 32 + o] * sc1c + sh1c) - fctr;
      } else v = fctr;
      e2lds[k * 64 + o] = v;
    }
    __syncthreads();
    #pragma unroll
    for (int i = 0; i < 8; ++i) {
      int k = wv + 4 * i;
      const float4* ep = (const float4*)(e2lds + k * 64);
      float acc = 0.f;
      #pragma unroll
      for (int j = 0; j < 16; ++j) {
        float4 e = ep[j];
        acc = fmaf(e.x, w2r[j].x, acc); acc = fmaf(e.y, w2r[j].y, acc);
        acc = fmaf(e.z, w2r[j].z, acc); acc = fmaf(e.w, w2r[j].w, acc);
      }
      ls += acc; lss += acc * acc;
    }
    __syncthreads();
  }
  sred[tid] = ls; sred2[tid] = lss;
  __syncthreads();
  if (tid < 64) {
    float s  = sred[tid] + sred[tid + 64] + sred[tid + 128] + sred[tid + 192];
    float ss = sred2[tid] + sred2[tid + 64] + sred2[tid + 128] + sred2[tid + 192];
    int slot = blockIdx.x & 255;
    atomicAdd(&slotsH2[slot * 128 + tid], (double)s);
    atomicAdd(&slotsH2[slot * 128 + 64 + tid], (double)ss);
  }
}

// ====== K8: h2 recompute + BN/lrelu + h3 stats + channel max — 16 rows/block ======
#define ROWS3 16
__global__ __launch_bounds__(256) void h3_kernel(
    const float* __restrict__ h1max, const int* __restrict__ idx_fps,
    const float* __restrict__ W2, const float* __restrict__ W3,
    const float* __restrict__ scsh1, const float* __restrict__ scsh2,
    double* __restrict__ slotsH3, float* __restrict__ h3max)
{
  __shared__ float e2lds[2048];
  __shared__ float h2lds[2048];
  __shared__ float wmax[256];
  __shared__ float sred[256], sred2[256];
  int tid = threadIdx.x;
  int o = tid & 63, wv = tid >> 6;
  float4 w2r[16], w3r[16];
  const float4* w2p = (const float4*)(W2 + o * 64);
  const float4* w3p = (const float4*)(W3 + o * 64);
  #pragma unroll
  for (int j = 0; j < 16; ++j) { w2r[j] = w2p[j]; w3r[j] = w3p[j]; }
  float sc2o = scsh2[o], sh2o = scsh2[64 + o];
  int cc = (o < 32) ? o : (o - 32);
  float sc1c = scsh1[cc], sh1c = scsh1[32 + cc];
  float ls = 0.f, lss = 0.f;
  int rbase = blockIdx.x * ROWS3;

  for (int row = 0; row < ROWS3; ++row) {
    int r = rbase + row;
    int broff = r & ~4095;
    float fctr = lrelu(h1max[(size_t)r * 32 + cc] * sc1c + sh1c);
    #pragma unroll
    for (int i = 0; i < 8; ++i) {
      int k = wv + 4 * i;
      float v;
      if (o < 32) {
        int nid = idx_fps[r * 32 + k];
        v = lrelu(h1max[(size_t)(broff + nid) * 32 + o] * sc1c + sh1c) - fctr;
      } else v = fctr;
      e2lds[k * 64 + o] = v;
    }
    __syncthreads();
    // phase1: h2post for this wave's k's
    #pragma unroll
    for (int i = 0; i < 8; ++i) {
      int k = wv + 4 * i;
      const float4* ep = (const float4*)(e2lds + k * 64);
      float acc = 0.f;
      #pragma unroll
      for (int j = 0; j < 16; ++j) {
        float4 e = ep[j];
        acc = fmaf(e.x, w2r[j].x, acc); acc = fmaf(e.y, w2r[j].y, acc);
        acc = fmaf(e.z, w2r[j].z, acc); acc = fmaf(e.w, w2r[j].w, acc);
      }
      h2lds[k * 64 + o] = lrelu(acc * sc2o + sh2o);
    }
    __syncthreads();
    // phase2: h3 pre-act, stats, per-lane max
    float kmax = -3.4e38f;
    #pragma unroll
    for (int i = 0; i < 8; ++i) {
      int k = wv + 4 * i;
      const float4* hp = (const float4*)(h2lds + k * 64);
      float acc = 0.f;
      #pragma unroll
      for (int j = 0; j < 16; ++j) {
        float4 h = hp[j];
        acc = fmaf(h.x, w3r[j].x, acc); acc = fmaf(h.y, w3r[j].y, acc);
        acc = fmaf(h.z, w3r[j].z, acc); acc = fmaf(h.w, w3r[j].w, acc);
      }
      ls += acc; lss += acc * acc;
      kmax = fmaxf(kmax, acc);
    }
    wmax[wv * 64 + o] = kmax;
    __syncthreads();
    if (tid < 64) {
      float m = fmaxf(fmaxf(wmax[tid], wmax[64 + tid]), fmaxf(wmax[128 + tid], wmax[192 + tid]));
      h3max[(size_t)r * 64 + tid] = m;
    }
  }
  sred[tid] = ls; sred2[tid] = lss;
  __syncthreads();
  if (tid < 64) {
    float s  = sred[tid] + sred[tid + 64] + sred[tid + 128] + sred[tid + 192];
    float ss = sred2[tid] + sred2[tid + 64] + sred2[tid + 128] + sred2[tid + 192];
    int slot = blockIdx.x & 255;
    atomicAdd(&slotsH3[slot * 128 + tid], (double)s);
    atomicAdd(&slotsH3[slot * 128 + 64 + tid], (double)ss);
  }
}

// ---------------- K10: out = lrelu(affine(h3max)) ----------------
__global__ void out_kernel(const float* __restrict__ h3max, const float* __restrict__ scsh3,
                           float* __restrict__ out)
{
  int i = blockIdx.x * 256 + threadIdx.x;
  int o = i & 63;
  out[i] = lrelu(h3max[i] * scsh3[o] + scsh3[64 + o]);
}

extern "C" void kernel_launch(void* const* d_in, const int* in_sizes, int n_in,
                              void* d_out, int out_size, void* d_ws, size_t ws_size,
                              hipStream_t stream) {
  (void)in_sizes; (void)n_in; (void)out_size; (void)ws_size;
  const float* x   = (const float*)d_in[0];
  const float* pos = (const float*)d_in[1];
  const float* W1  = (const float*)d_in[2];
  const float* g1  = (const float*)d_in[3];
  const float* b1  = (const float*)d_in[4];
  const float* W2  = (const float*)d_in[5];
  const float* g2  = (const float*)d_in[6];
  const float* b2  = (const float*)d_in[7];
  const float* W3  = (const float*)d_in[8];
  const float* g3  = (const float*)d_in[9];
  const float* b3  = (const float*)d_in[10];

  float* out      = (float*)d_out;             // (4,4096,64) f32
  float* out_idx1 = out + 1048576;             // (4,4096,14) written as float(idx)

  char* ws = (char*)d_ws;
  double* slotsH1 = (double*)(ws + 0);         // 256 x 64 double
  double* slotsH2 = (double*)(ws + 131072);    // 256 x 128 double
  double* slotsH3 = (double*)(ws + 393216);    // 256 x 128 double
  float*  scsh1   = (float*)(ws + 655360);     // 64 f
  float*  scsh2   = (float*)(ws + 655616);     // 128 f
  float*  scsh3   = (float*)(ws + 656128);     // 128 f
  int*    idx_l   = (int*)(ws + 1048576);      // 16384 x 128
  int*    idx_fps = (int*)(ws + 9437184);      // 16384 x 32
  int*    idx1_i  = (int*)(ws + 11534336);     // 16384 x 14
  float*  h1max   = (float*)(ws + 12451840);   // 16384 x 32
  float*  h3max   = (float*)(ws + 16646144);   // 16384 x 64

  hipMemsetAsync(d_ws, 0, 656640, stream);     // zero stat accumulators

  knn_pos_kernel <<<dim3(2048),  dim3(512), 0, stream>>>(pos, idx_l, idx1_i, out_idx1);
  knn_feat_kernel<<<dim3(2048),  dim3(512), 0, stream>>>(x, idx1_i, out_idx1);
  fps_kernel     <<<dim3(4096),  dim3(256), 0, stream>>>(pos, idx_l, idx_fps);
  h1_kernel      <<<dim3(512),   dim3(256), 0, stream>>>(x, idx1_i, W1, slotsH1, h1max);
  finalize_stats_kernel<<<dim3(1), dim3(64), 0, stream>>>(slotsH1, 32, 229376.0, g1, b1, scsh1);
  h2_stats_kernel<<<dim3(1024),  dim3(256), 0, stream>>>(h1max, idx_fps, W2, scsh1, slotsH2);
  finalize_stats_kernel<<<dim3(1), dim3(64), 0, stream>>>(slotsH2, 64, 524288.0, g2, b2, scsh2);
  h3_kernel      <<<dim3(1024),  dim3(256), 0, stream>>>(h1max, idx_fps, W2, W3, scsh1, scsh2, slotsH3, h3max);
  finalize_stats_kernel<<<dim3(1), dim3(64), 0, stream>>>(slotsH3, 64, 524288.0, g3, b3, scsh3);
  out_kernel     <<<dim3(4096),  dim3(256), 0, stream>>>(h3max, scsh3, out);
}

// Round 5
// 786.585 us; speedup vs baseline: 3.9046x; 1.8051x over previous
//
#include <hip/hip_runtime.h>

#define NPTS 4096
#define BNROWS 16384

__device__ __forceinline__ float lrelu(float h) { return h > 0.f ? h : 0.2f * h; }

// ================= K1: pos 128-NN (sorted) + idx_pos ==================
__global__ __launch_bounds__(512) void knn_pos_kernel(
    const float* __restrict__ pos, int* __restrict__ idx_l,
    int* __restrict__ idx1_i, float* __restrict__ idx1_f)
{
  __shared__ unsigned long long cKey[8][512];
  __shared__ int cIdx[8][512];
  __shared__ unsigned int cCnt[8];
  int tid = threadIdx.x;
  int w = tid >> 6, lane = tid & 63;
  int r = blockIdx.x * 8 + w;
  int b = r >> 12, n = r & 4095;
  const float* pb = pos + (size_t)b * NPTS * 3;
  float cx = pb[n*3+0], cy = pb[n*3+1], cz = pb[n*3+2];
  if (lane == 0) cCnt[w] = 0u;

  unsigned int qp[32];
  int m1 = 65536, m2 = 65536, m3 = 65536;
  #pragma unroll
  for (int t = 0; t < 32; ++t) {
    unsigned int wq = 0u;
    #pragma unroll
    for (int h = 0; h < 2; ++h) {
      int j = (2*t + h) * 64 + lane;
      float dx = cx - pb[j*3+0], dy = cy - pb[j*3+1], dz = cz - pb[j*3+2];
      float d2 = dx*dx + dy*dy + dz*dz;
      int q = (int)(d2 * 1000.0f);
      q = q < 0 ? 0 : (q > 65535 ? 65535 : q);
      wq |= ((unsigned int)q) << (16*h);
      int nm1 = min(m1, q);
      int nm2 = min(m2, max(m1, q));
      int nm3 = min(m3, max(m2, q));
      m1 = nm1; m2 = nm2; m3 = nm3;
    }
    qp[t] = wq;
  }
  int lo = 0, hi = 65535;
  #pragma unroll
  for (int it = 0; it < 16; ++it) {
    int mid = (lo + hi) >> 1;
    int cnt = __popcll(__ballot(m3 <= mid));
    if (cnt >= 43) hi = mid; else lo = mid + 1;
  }
  unsigned int qt = (unsigned int)lo + 2u;

  #pragma unroll
  for (int t = 0; t < 32; ++t) {
    unsigned int wq = qp[t];
    unsigned int q0 = wq & 0xffffu, q1 = wq >> 16;
    if (q0 <= qt) { unsigned int p = atomicAdd(&cCnt[w], 1u); if (p < 512u) cIdx[w][p] = (2*t)*64 + lane; }
    if (q1 <= qt) { unsigned int p = atomicAdd(&cCnt[w], 1u); if (p < 512u) cIdx[w][p] = (2*t+1)*64 + lane; }
  }
  __syncthreads();
  unsigned int nc = cCnt[w]; if (nc > 512u) nc = 512u;

  double cxd = (double)cx, cyd = (double)cy, czd = (double)cz;
  #pragma unroll
  for (int t = 0; t < 8; ++t) {
    int c = lane + 64*t;
    unsigned long long kk = ~0ull; int id = 0x7fffffff;
    if (c < (int)nc) {
      id = cIdx[w][c];
      double dx = cxd - (double)pb[id*3+0];
      double dy = cyd - (double)pb[id*3+1];
      double dz = czd - (double)pb[id*3+2];
      kk = (unsigned long long)__double_as_longlong(dx*dx + dy*dy + dz*dz);
    }
    cKey[w][c] = kk; cIdx[w][c] = id;
  }
  __syncthreads();

  for (int k = 2; k <= 512; k <<= 1) {
    for (int j = k >> 1; j > 0; j >>= 1) {
      #pragma unroll
      for (int t = 0; t < 8; ++t) {
        int i = lane + 64*t;
        int ixj = i ^ j;
        if (ixj > i) {
          unsigned long long ka = cKey[w][i], kb = cKey[w][ixj];
          int ia = cIdx[w][i], ib = cIdx[w][ixj];
          bool agtb = (ka > kb) || (ka == kb && ia > ib);
          bool up = ((i & k) == 0);
          if (agtb == up) { cKey[w][i] = kb; cKey[w][ixj] = ka; cIdx[w][i] = ib; cIdx[w][ixj] = ia; }
        }
      }
      __syncthreads();
    }
  }
  idx_l[(size_t)r * 128 + lane]      = cIdx[w][lane];
  idx_l[(size_t)r * 128 + lane + 64] = cIdx[w][lane + 64];
  if (lane < 6) {
    int v = cIdx[w][1 + lane];
    idx1_i[r * 14 + 8 + lane] = v;
    idx1_f[r * 14 + 8 + lane] = (float)v;
  }
}

// ================= K2: feature 8-NN (excl self) ==================
__global__ __launch_bounds__(512) void knn_feat_kernel(
    const float* __restrict__ x, int* __restrict__ idx1_i, float* __restrict__ idx1_f)
{
  __shared__ float ctrf[8][16];
  __shared__ float4 cm2[8][5];
  __shared__ unsigned short lmin[8][512];
  __shared__ int cand[8][192];
  __shared__ unsigned int cCnt[8];
  __shared__ unsigned short qtS[8];
  int tid = threadIdx.x;
  int rbase = blockIdx.x * 8;
  int b = rbase >> 12;
  const float* xb = x + (size_t)b * NPTS * 16;

  if (tid < 128) {
    int rr = tid >> 4, c = tid & 15;
    float v = xb[(size_t)((rbase + rr) & 4095) * 16 + c];
    ctrf[rr][c] = v;
    ((float*)&cm2[rr][0])[c] = -2.0f * v;
  }
  if (tid < 8) cCnt[tid] = 0u;
  __syncthreads();
  if (tid < 8) {
    float s = 0.f;
    for (int c = 0; c < 16; ++c) { float v = ctrf[tid][c]; s += v * v; }
    cm2[tid][4].x = s;
  }
  __syncthreads();

  unsigned int qp[8][4];
  int minq[8];
  #pragma unroll
  for (int r = 0; r < 8; ++r) minq[r] = 65536;

  #pragma unroll
  for (int pp = 0; pp < 4; ++pp) {
    int j0 = tid + 512 * (2*pp);
    int j1 = j0 + 512;
    const float4* xj0 = (const float4*)(xb + (size_t)j0 * 16);
    const float4* xj1 = (const float4*)(xb + (size_t)j1 * 16);
    float4 a0 = xj0[0], a1 = xj0[1], a2 = xj0[2], a3 = xj0[3];
    float4 b0 = xj1[0], b1 = xj1[1], b2 = xj1[2], b3 = xj1[3];
    float va[16] = {a0.x,a0.y,a0.z,a0.w, a1.x,a1.y,a1.z,a1.w,
                    a2.x,a2.y,a2.z,a2.w, a3.x,a3.y,a3.z,a3.w};
    float vb[16] = {b0.x,b0.y,b0.z,b0.w, b1.x,b1.y,b1.z,b1.w,
                    b2.x,b2.y,b2.z,b2.w, b3.x,b3.y,b3.z,b3.w};
    float pna = 0.f, pnb = 0.f;
    #pragma unroll
    for (int c = 0; c < 16; ++c) { pna = fmaf(va[c], va[c], pna); pnb = fmaf(vb[c], vb[c], pnb); }
    #pragma unroll
    for (int r = 0; r < 8; ++r) {
      float4 m0 = cm2[r][0], m1 = cm2[r][1], m2 = cm2[r][2], m3 = cm2[r][3];
      float c2 = cm2[r][4].x;
      float wm[16] = {m0.x,m0.y,m0.z,m0.w, m1.x,m1.y,m1.z,m1.w,
                      m2.x,m2.y,m2.z,m2.w, m3.x,m3.y,m3.z,m3.w};
      float aa = pna + c2, ab = pnb + c2;
      #pragma unroll
      for (int c = 0; c < 16; ++c) { aa = fmaf(wm[c], va[c], aa); ab = fmaf(wm[c], vb[c], ab); }
      int qa = (int)(aa * 400.0f); qa = qa < 0 ? 0 : (qa > 65535 ? 65535 : qa);
      int qb = (int)(ab * 400.0f); qb = qb < 0 ? 0 : (qb > 65535 ? 65535 : qb);
      qp[r][pp] = (unsigned int)qa | ((unsigned int)qb << 16);
      minq[r] = min(minq[r], min(qa, qb));
    }
  }
  #pragma unroll
  for (int r = 0; r < 8; ++r) lmin[r][tid] = (unsigned short)minq[r];
  __syncthreads();

  int w = tid >> 6, lane = tid & 63;
  {
    unsigned short lv[8];
    #pragma unroll
    for (int t = 0; t < 8; ++t) lv[t] = lmin[w][lane + 64*t];
    int lo = 0, hi = 65535;
    #pragma unroll
    for (int it = 0; it < 16; ++it) {
      int mid = (lo + hi) >> 1;
      int cnt = 0;
      #pragma unroll
      for (int t = 0; t < 8; ++t) cnt += __popcll(__ballot((int)lv[t] <= mid));
      if (cnt >= 10) hi = mid; else lo = mid + 1;
    }
    if (lane == 0) qtS[w] = (unsigned short)min(lo + 2, 65535);
  }
  __syncthreads();

  {
    unsigned int qts[8];
    #pragma unroll
    for (int r = 0; r < 8; ++r) qts[r] = qtS[r];
    #pragma unroll
    for (int r = 0; r < 8; ++r) {
      #pragma unroll
      for (int pp = 0; pp < 4; ++pp) {
        unsigned int wq = qp[r][pp];
        unsigned int q0 = wq & 0xffffu, q1 = wq >> 16;
        if (q0 <= qts[r]) { unsigned int p = atomicAdd(&cCnt[r], 1u); if (p < 192u) cand[r][p] = tid + 512*(2*pp); }
        if (q1 <= qts[r]) { unsigned int p = atomicAdd(&cCnt[r], 1u); if (p < 192u) cand[r][p] = tid + 512*(2*pp+1); }
      }
    }
  }
  __syncthreads();

  {
    int nc = (int)cCnt[w]; if (nc > 192) nc = 192;
    double key[3]; int kid[3];
    #pragma unroll
    for (int s = 0; s < 3; ++s) {
      int c = lane + 64*s;
      if (c < nc) {
        int id = cand[w][c];
        const float4* xp = (const float4*)(xb + (size_t)id * 16);
        float4 q0 = xp[0], q1 = xp[1], q2 = xp[2], q3 = xp[3];
        float xv[16] = {q0.x,q0.y,q0.z,q0.w, q1.x,q1.y,q1.z,q1.w,
                        q2.x,q2.y,q2.z,q2.w, q3.x,q3.y,q3.z,q3.w};
        double acc = 0.0;
        #pragma unroll
        for (int c2 = 0; c2 < 16; ++c2) { double d = (double)ctrf[w][c2] - (double)xv[c2]; acc += d * d; }
        key[s] = acc; kid[s] = id;
      } else { key[s] = 1e300; kid[s] = 0x7fffffff; }
    }
    int row = rbase + w;
    for (int it = 0; it < 9; ++it) {
      double bk = key[0]; int bi = kid[0], bs = 0;
      if (key[1] < bk || (key[1] == bk && kid[1] < bi)) { bk = key[1]; bi = kid[1]; bs = 1; }
      if (key[2] < bk || (key[2] == bk && kid[2] < bi)) { bk = key[2]; bi = kid[2]; bs = 2; }
      double rk = bk; int ri = bi;
      #pragma unroll
      for (int off = 32; off > 0; off >>= 1) {
        double ok = __shfl_xor(rk, off, 64);
        int oi = __shfl_xor(ri, off, 64);
        if (ok < rk || (ok == rk && oi < ri)) { rk = ok; ri = oi; }
      }
      if (it > 0 && lane == 0) {
        idx1_i[row * 14 + it - 1] = ri;
        idx1_f[row * 14 + it - 1] = (float)ri;
      }
      if (bi == ri) key[bs] = 1e300;
    }
  }
}

// ================= K3: FPS (replicates reference's batch-0 gather) =============
__global__ __launch_bounds__(256) void fps_kernel(
    const float* __restrict__ pos, const int* __restrict__ idx_l, int* __restrict__ idx_fps)
{
  int wave = threadIdx.x >> 6, lane = threadIdx.x & 63;
  int r = blockIdx.x * 4 + wave;
  const int* il = idx_l + (size_t)r * 128;
  int gi0 = il[lane], gi1 = il[lane + 64];
  double x0 = (double)pos[gi0*3+0], y0 = (double)pos[gi0*3+1], z0 = (double)pos[gi0*3+2];
  double x1 = (double)pos[gi1*3+0], y1 = (double)pos[gi1*3+1], z1 = (double)pos[gi1*3+2];
  double d0 = 1e10, d1 = 1e10;
  int far = 0;
  int* outp = idx_fps + (size_t)r * 32;
  for (int i = 0; i < 32; ++i) {
    int ownerLane = far & 63;
    int sel = far >> 6;
    int gsel = sel ? gi1 : gi0;
    int gout = __shfl(gsel, ownerLane, 64);
    if (lane == 0) outp[i] = gout;
    double cx = __shfl(sel ? x1 : x0, ownerLane, 64);
    double cy = __shfl(sel ? y1 : y0, ownerLane, 64);
    double cz = __shfl(sel ? z1 : z0, ownerLane, 64);
    double t0 = (x0-cx)*(x0-cx) + (y0-cy)*(y0-cy) + (z0-cz)*(z0-cz);
    double t1 = (x1-cx)*(x1-cx) + (y1-cy)*(y1-cy) + (z1-cz)*(z1-cz);
    d0 = fmin(d0, t0); d1 = fmin(d1, t1);
    double v; int p;
    if (d1 > d0) { v = d1; p = lane + 64; } else { v = d0; p = lane; }
    for (int off = 32; off > 0; off >>= 1) {
      double ov = __shfl_xor(v, off, 64);
      int op = __shfl_xor(p, off, 64);
      if (ov > v || (ov == v && op < p)) { v = ov; p = op; }
    }
    far = p;
  }
}

// ========== K4a: s[gr][o] = x[gr]·W1a[o], v[gr][o] = x[gr]·(W1b-W1a)[o] ==========
__global__ __launch_bounds__(256) void sv_kernel(
    const float* __restrict__ x, const float* __restrict__ W1,
    float* __restrict__ s, float* __restrict__ v)
{
  __shared__ float xs[8][16];
  __shared__ float w1t[512], w1dt[512];
  int tid = threadIdx.x;
  int rbase = blockIdx.x * 8;
  for (int i = tid; i < 512; i += 256) {
    int c = i >> 5, o = i & 31;
    float a = W1[o * 32 + c], bb = W1[o * 32 + 16 + c];
    w1t[i] = a; w1dt[i] = bb - a;
  }
  if (tid < 128) { int rr = tid >> 4, c = tid & 15; xs[rr][c] = x[(size_t)(rbase + rr) * 16 + c]; }
  __syncthreads();
  int rr = tid >> 5, o = tid & 31;
  float sa = 0.f, va = 0.f;
  #pragma unroll
  for (int c = 0; c < 16; ++c) {
    float xv = xs[rr][c];
    sa = fmaf(xv, w1t[c * 32 + o], sa);
    va = fmaf(xv, w1dt[c * 32 + o], va);
  }
  int r = rbase + rr;
  s[(size_t)r * 32 + o] = sa;
  v[(size_t)r * 32 + o] = va;
}

// ========== K4b: h1max + h1 stats via gathered s + v ==========
__global__ __launch_bounds__(256) void h1stats_kernel(
    const float* __restrict__ s, const float* __restrict__ v, const int* __restrict__ idx1_i,
    double* __restrict__ slotsH1, float* __restrict__ h1max)
{
  __shared__ int sidx[8][14];
  __shared__ float sred[256], sred2[256];
  int tid = threadIdx.x;
  int rr = tid >> 5, o = tid & 31;
  int rbase = blockIdx.x * 8;
  if (tid < 112) { int q = tid / 14, k = tid % 14; sidx[q][k] = idx1_i[(rbase + q) * 14 + k]; }
  __syncthreads();
  int r = rbase + rr;
  int broff = r & ~4095;
  float vv = v[(size_t)r * 32 + o];
  float m = -3.4e38f, ls = 0.f, lss = 0.f;
  #pragma unroll
  for (int k = 0; k < 14; ++k) {
    int j = sidx[rr][k];
    float val = s[(size_t)(broff + j) * 32 + o] + vv;
    m = fmaxf(m, val);
    ls += val; lss += val * val;
  }
  h1max[(size_t)r * 32 + o] = m;
  sred[tid] = ls; sred2[tid] = lss;
  __syncthreads();
  if (tid < 32) {
    float s2 = 0.f, ss = 0.f;
    #pragma unroll
    for (int j = 0; j < 8; ++j) { s2 += sred[j * 32 + tid]; ss += sred2[j * 32 + tid]; }
    int slot = blockIdx.x & 255;
    atomicAdd(&slotsH1[slot * 64 + tid], (double)s2);
    atomicAdd(&slotsH1[slot * 64 + 32 + tid], (double)ss);
  }
}

// ---------------- stats finalize: scsh = [sc(C), sh(C)] ----------------
__global__ void finalize_stats_kernel(const double* __restrict__ slots, int C, double cnt,
    const float* __restrict__ g, const float* __restrict__ bta, float* __restrict__ scsh)
{
  int o = threadIdx.x;
  if (o < C) {
    double s = 0.0, ss = 0.0;
    for (int slot = 0; slot < 256; ++slot) { s += slots[slot * 2 * C + o]; ss += slots[slot * 2 * C + C + o]; }
    double mu = s / cnt;
    double var = ss / cnt - mu * mu;
    double rs = 1.0 / sqrt(var + 1e-5);
    float sc = (float)rs * g[o];
    float sh = bta[o] - (float)mu * sc;
    scsh[o] = sc;
    scsh[C + o] = sh;
  }
}

// ========== K5a: f1 = lrelu(affine(h1max)); t = f1·W2a, u = f1·(W2b-W2a) ==========
__global__ __launch_bounds__(256) void tu_kernel(
    const float* __restrict__ h1max, const float* __restrict__ scsh1, const float* __restrict__ W2,
    float* __restrict__ t, float* __restrict__ u)
{
  __shared__ float f1s[4][32];
  __shared__ float w2t[2048], w2dt[2048];
  int tid = threadIdx.x;
  int rbase = blockIdx.x * 4;
  for (int i = tid; i < 2048; i += 256) {
    int c = i >> 6, o = i & 63;
    float a = W2[o * 64 + c], bb = W2[o * 64 + 32 + c];
    w2t[i] = a; w2dt[i] = bb - a;
  }
  if (tid < 128) {
    int rr = tid >> 5, c = tid & 31;
    f1s[rr][c] = lrelu(h1max[(size_t)(rbase + rr) * 32 + c] * scsh1[c] + scsh1[32 + c]);
  }
  __syncthreads();
  int rr = tid >> 6, o = tid & 63;
  float ta = 0.f, ua = 0.f;
  #pragma unroll
  for (int c = 0; c < 32; ++c) {
    float fv = f1s[rr][c];
    ta = fmaf(fv, w2t[c * 64 + o], ta);
    ua = fmaf(fv, w2dt[c * 64 + o], ua);
  }
  int r = rbase + rr;
  t[(size_t)r * 64 + o] = ta;
  u[(size_t)r * 64 + o] = ua;
}

// ========== K5b: h2 stats via gathered t + u ==========
__global__ __launch_bounds__(256) void h2stats_kernel(
    const float* __restrict__ t, const float* __restrict__ u, const int* __restrict__ idx_fps,
    double* __restrict__ slotsH2)
{
  __shared__ int nids[8][32];
  __shared__ float sred[256], sred2[256];
  int tid = threadIdx.x;
  int o = tid & 63, wv = tid >> 6;
  int rbase = blockIdx.x * 8;
  { int q = tid >> 5, k = tid & 31; nids[q][k] = idx_fps[(rbase + q) * 32 + k]; }
  __syncthreads();
  float ls = 0.f, lss = 0.f;
  for (int rr = 0; rr < 8; ++rr) {
    int r = rbase + rr;
    int broff = r & ~4095;
    float uo = u[(size_t)r * 64 + o];
    #pragma unroll
    for (int i = 0; i < 8; ++i) {
      int k = wv + 4 * i;
      float val = t[(size_t)(broff + nids[rr][k]) * 64 + o] + uo;
      ls += val; lss += val * val;
    }
  }
  sred[tid] = ls; sred2[tid] = lss;
  __syncthreads();
  if (tid < 64) {
    float s2 = sred[tid] + sred[tid + 64] + sred[tid + 128] + sred[tid + 192];
    float ss = sred2[tid] + sred2[tid + 64] + sred2[tid + 128] + sred2[tid + 192];
    int slot = blockIdx.x & 255;
    atomicAdd(&slotsH2[slot * 128 + tid], (double)s2);
    atomicAdd(&slotsH2[slot * 128 + 64 + tid], (double)ss);
  }
}

// ========== K6: h3 = lrelu(affine(t[nid]+u))·W3ᵀ, stats + channel max ==========
#define ROWS3 8
__global__ __launch_bounds__(256, 4) void h3_kernel(
    const float* __restrict__ t, const float* __restrict__ u, const int* __restrict__ idx_fps,
    const float* __restrict__ W3, const float* __restrict__ scsh2,
    double* __restrict__ slotsH3, float* __restrict__ h3max)
{
  __shared__ float h2lds[2048];
  __shared__ float wmax[256];
  __shared__ float sred[256], sred2[256];
  __shared__ int nids[ROWS3][32];
  int tid = threadIdx.x;
  int o = tid & 63, wv = tid >> 6;
  float4 w3r[16];
  const float4* w3p = (const float4*)(W3 + o * 64);
  #pragma unroll
  for (int j = 0; j < 16; ++j) w3r[j] = w3p[j];
  float sc2o = scsh2[o], sh2o = scsh2[64 + o];
  int rbase = blockIdx.x * ROWS3;
  { int q = tid >> 5, k = tid & 31; nids[q][k] = idx_fps[(rbase + q) * 32 + k]; }
  float ls = 0.f, lss = 0.f;
  __syncthreads();
  for (int rr = 0; rr < ROWS3; ++rr) {
    int r = rbase + rr;
    int broff = r & ~4095;
    float uo = u[(size_t)r * 64 + o];
    #pragma unroll
    for (int i = 0; i < 8; ++i) {
      int k = wv + 4 * i;
      float val = t[(size_t)(broff + nids[rr][k]) * 64 + o] + uo;
      h2lds[k * 64 + o] = lrelu(val * sc2o + sh2o);
    }
    __syncthreads();
    float kmax = -3.4e38f;
    #pragma unroll
    for (int i = 0; i < 8; ++i) {
      int k = wv + 4 * i;
      const float4* hp = (const float4*)(h2lds + k * 64);
      float acc = 0.f;
      #pragma unroll
      for (int j = 0; j < 16; ++j) {
        float4 h = hp[j];
        acc = fmaf(h.x, w3r[j].x, acc); acc = fmaf(h.y, w3r[j].y, acc);
        acc = fmaf(h.z, w3r[j].z, acc); acc = fmaf(h.w, w3r[j].w, acc);
      }
      ls += acc; lss += acc * acc;
      kmax = fmaxf(kmax, acc);
    }
    wmax[tid] = kmax;
    __syncthreads();
    if (tid < 64) {
      float m = fmaxf(fmaxf(wmax[tid], wmax[64 + tid]), fmaxf(wmax[128 + tid], wmax[192 + tid]));
      h3max[(size_t)r * 64 + tid] = m;
    }
  }
  sred[tid] = ls; sred2[tid] = lss;
  __syncthreads();
  if (tid < 64) {
    float s2 = sred[tid] + sred[tid + 64] + sred[tid + 128] + sred[tid + 192];
    float ss = sred2[tid] + sred2[tid + 64] + sred2[tid + 128] + sred2[tid + 192];
    int slot = blockIdx.x & 255;
    atomicAdd(&slotsH3[slot * 128 + tid], (double)s2);
    atomicAdd(&slotsH3[slot * 128 + 64 + tid], (double)ss);
  }
}

// ---------------- K10: out = lrelu(affine(h3max)) ----------------
__global__ void out_kernel(const float* __restrict__ h3max, const float* __restrict__ scsh3,
                           float* __restrict__ out)
{
  int i = blockIdx.x * 256 + threadIdx.x;
  int o = i & 63;
  out[i] = lrelu(h3max[i] * scsh3[o] + scsh3[64 + o]);
}

extern "C" void kernel_launch(void* const* d_in, const int* in_sizes, int n_in,
                              void* d_out, int out_size, void* d_ws, size_t ws_size,
                              hipStream_t stream) {
  (void)in_sizes; (void)n_in; (void)out_size; (void)ws_size;
  const float* x   = (const float*)d_in[0];
  const float* pos = (const float*)d_in[1];
  const float* W1  = (const float*)d_in[2];
  const float* g1  = (const float*)d_in[3];
  const float* b1  = (const float*)d_in[4];
  const float* W2  = (const float*)d_in[5];
  const float* g2  = (const float*)d_in[6];
  const float* b2  = (const float*)d_in[7];
  const float* W3  = (const float*)d_in[8];
  const float* g3  = (const float*)d_in[9];
  const float* b3  = (const float*)d_in[10];

  float* out      = (float*)d_out;             // (4,4096,64) f32
  float* out_idx1 = out + 1048576;             // (4,4096,14) written as float(idx)

  char* ws = (char*)d_ws;
  double* slotsH1 = (double*)(ws + 0);         // 256 x 64 double
  double* slotsH2 = (double*)(ws + 131072);    // 256 x 128 double
  double* slotsH3 = (double*)(ws + 393216);    // 256 x 128 double
  float*  scsh1   = (float*)(ws + 655360);     // 64 f
  float*  scsh2   = (float*)(ws + 655616);     // 128 f
  float*  scsh3   = (float*)(ws + 656128);     // 128 f
  int*    idx_l   = (int*)(ws + 1048576);      // 16384 x 128 (freed after fps)
  float*  t_buf   = (float*)(ws + 1048576);    // 16384 x 64 f32 (overlaps idx_l)
  float*  u_buf   = (float*)(ws + 5242880);    // 16384 x 64 f32 (overlaps idx_l)
  int*    idx_fps = (int*)(ws + 9437184);      // 16384 x 32
  int*    idx1_i  = (int*)(ws + 11534336);     // 16384 x 14
  float*  h1max   = (float*)(ws + 12451840);   // 16384 x 32
  float*  s_buf   = (float*)(ws + 14548992);   // 16384 x 32
  float*  v_buf   = (float*)(ws + 16646144);   // 16384 x 32
  float*  h3max   = (float*)(ws + 18743296);   // 16384 x 64

  hipMemsetAsync(d_ws, 0, 656640, stream);     // zero stat accumulators

  knn_pos_kernel <<<dim3(2048), dim3(512), 0, stream>>>(pos, idx_l, idx1_i, out_idx1);
  knn_feat_kernel<<<dim3(2048), dim3(512), 0, stream>>>(x, idx1_i, out_idx1);
  fps_kernel     <<<dim3(4096), dim3(256), 0, stream>>>(pos, idx_l, idx_fps);
  // idx_l dead from here; t/u reuse its space
  sv_kernel      <<<dim3(2048), dim3(256), 0, stream>>>(x, W1, s_buf, v_buf);
  h1stats_kernel <<<dim3(2048), dim3(256), 0, stream>>>(s_buf, v_buf, idx1_i, slotsH1, h1max);
  finalize_stats_kernel<<<dim3(1), dim3(64), 0, stream>>>(slotsH1, 32, 229376.0, g1, b1, scsh1);
  tu_kernel      <<<dim3(4096), dim3(256), 0, stream>>>(h1max, scsh1, W2, t_buf, u_buf);
  h2stats_kernel <<<dim3(2048), dim3(256), 0, stream>>>(t_buf, u_buf, idx_fps, slotsH2);
  finalize_stats_kernel<<<dim3(1), dim3(64), 0, stream>>>(slotsH2, 64, 524288.0, g2, b2, scsh2);
  h3_kernel      <<<dim3(2048), dim3(256), 0, stream>>>(t_buf, u_buf, idx_fps, W3, scsh2, slotsH3, h3max);
  finalize_stats_kernel<<<dim3(1), dim3(64), 0, stream>>>(slotsH3, 64, 524288.0, g3, b3, scsh3);
  out_kernel     <<<dim3(4096), dim3(256), 0, stream>>>(h3max, scsh3, out);
}

// Round 6
// 654.321 us; speedup vs baseline: 4.6939x; 1.2021x over previous
//
#include <hip/hip_runtime.h>

#define NPTS 4096
#define BNROWS 16384

__device__ __forceinline__ float lrelu(float h) { return h > 0.f ? h : 0.2f * h; }

// wave-local LDS fence: orders this wave's LDS ops (lockstep wave64 + lgkmcnt)
#define WSYNC asm volatile("s_waitcnt lgkmcnt(0)" ::: "memory")

// ================= K1: pos 128-NN (sorted) + idx_pos ==================
// 8 waves/block, one row per wave, NO block barriers: each wave sorts its
// private LDS slice of packed u64 keys ((fp64bits & ~0xFFF) | idx).
__global__ __launch_bounds__(512) void knn_pos_kernel(
    const float* __restrict__ pos, int* __restrict__ idx_l,
    int* __restrict__ idx1_i, float* __restrict__ idx1_f)
{
  __shared__ unsigned long long cKey[8][512];
  __shared__ unsigned int cCnt[8];
  int tid = threadIdx.x;
  int w = tid >> 6, lane = tid & 63;
  int r = blockIdx.x * 8 + w;
  int b = r >> 12, n = r & 4095;
  const float* pb = pos + (size_t)b * NPTS * 3;
  float cx = pb[n*3+0], cy = pb[n*3+1], cz = pb[n*3+2];
  if (lane == 0) cCnt[w] = 0u;
  WSYNC;

  unsigned int qp[32];
  int m1 = 65536, m2 = 65536, m3 = 65536;
  #pragma unroll
  for (int t = 0; t < 32; ++t) {
    unsigned int wq = 0u;
    #pragma unroll
    for (int h = 0; h < 2; ++h) {
      int j = (2*t + h) * 64 + lane;
      float dx = cx - pb[j*3+0], dy = cy - pb[j*3+1], dz = cz - pb[j*3+2];
      float d2 = dx*dx + dy*dy + dz*dz;
      int q = (int)(d2 * 1000.0f);
      q = q < 0 ? 0 : (q > 65535 ? 65535 : q);
      wq |= ((unsigned int)q) << (16*h);
      int nm1 = min(m1, q);
      int nm2 = min(m2, max(m1, q));
      int nm3 = min(m3, max(m2, q));
      m1 = nm1; m2 = nm2; m3 = nm3;
    }
    qp[t] = wq;
  }
  // smallest qt with >=43 lanes having 3rd-min <= qt  => >=129 pts <= qt
  int lo = 0, hi = 65535;
  #pragma unroll
  for (int it = 0; it < 16; ++it) {
    int mid = (lo + hi) >> 1;
    int cnt = __popcll(__ballot(m3 <= mid));
    if (cnt >= 43) hi = mid; else lo = mid + 1;
  }
  unsigned int qt = (unsigned int)lo + 2u;   // +2 bucket slack (fp32 vs fp64)

  // candidate compaction: store raw index into the key slots
  #pragma unroll
  for (int t = 0; t < 32; ++t) {
    unsigned int wq = qp[t];
    unsigned int q0 = wq & 0xffffu, q1 = wq >> 16;
    if (q0 <= qt) { unsigned int p = atomicAdd(&cCnt[w], 1u); if (p < 512u) cKey[w][p] = (unsigned long long)((2*t)*64 + lane); }
    if (q1 <= qt) { unsigned int p = atomicAdd(&cCnt[w], 1u); if (p < 512u) cKey[w][p] = (unsigned long long)((2*t+1)*64 + lane); }
  }
  WSYNC;
  unsigned int nc = cCnt[w]; if (nc > 512u) nc = 512u;
  int M = (nc <= 256u) ? 256 : 512;
  int EPL = M >> 6;   // elements per lane: 4 or 8

  // exact fp64 rerank in place -> packed (key|idx), pad with ~0
  double cxd = (double)cx, cyd = (double)cy, czd = (double)cz;
  for (int t = 0; t < EPL; ++t) {
    int c = lane + (t << 6);
    unsigned long long kk = ~0ull;
    if (c < (int)nc) {
      int id = (int)cKey[w][c];
      double dx = cxd - (double)pb[id*3+0];
      double dy = cyd - (double)pb[id*3+1];
      double dz = czd - (double)pb[id*3+2];
      double d2 = dx*dx + dy*dy + dz*dz;
      unsigned long long bits = (unsigned long long)__double_as_longlong(d2);
      kk = (bits & ~0xFFFull) | (unsigned long long)(unsigned int)id;
    }
    cKey[w][c] = kk;
  }
  WSYNC;

  // wave-private bitonic-M on packed keys, ascending
  for (int k = 2; k <= M; k <<= 1) {
    for (int j = k >> 1; j > 0; j >>= 1) {
      for (int t = 0; t < EPL; ++t) {
        int i = lane + (t << 6);
        int ixj = i ^ j;
        if (ixj > i) {
          unsigned long long ka = cKey[w][i], kb = cKey[w][ixj];
          bool up = ((i & k) == 0);
          if ((ka > kb) == up) { cKey[w][i] = kb; cKey[w][ixj] = ka; }
        }
      }
      WSYNC;
    }
  }
  idx_l[(size_t)r * 128 + lane]      = (int)(cKey[w][lane] & 0xFFFull);
  idx_l[(size_t)r * 128 + lane + 64] = (int)(cKey[w][lane + 64] & 0xFFFull);
  if (lane < 6) {
    int v = (int)(cKey[w][1 + lane] & 0xFFFull);
    idx1_i[r * 14 + 8 + lane] = v;
    idx1_f[r * 14 + 8 + lane] = (float)v;
  }
}

// ================= K2: feature 8-NN (excl self) ==================
__global__ __launch_bounds__(512) void knn_feat_kernel(
    const float* __restrict__ x, int* __restrict__ idx1_i, float* __restrict__ idx1_f)
{
  __shared__ float ctrf[8][16];
  __shared__ float4 cm2[8][5];
  __shared__ unsigned short lmin[8][512];
  __shared__ int cand[8][192];
  __shared__ unsigned int cCnt[8];
  __shared__ unsigned short qtS[8];
  int tid = threadIdx.x;
  int rbase = blockIdx.x * 8;
  int b = rbase >> 12;
  const float* xb = x + (size_t)b * NPTS * 16;

  if (tid < 128) {
    int rr = tid >> 4, c = tid & 15;
    float v = xb[(size_t)((rbase + rr) & 4095) * 16 + c];
    ctrf[rr][c] = v;
    ((float*)&cm2[rr][0])[c] = -2.0f * v;
  }
  if (tid < 8) cCnt[tid] = 0u;
  __syncthreads();
  if (tid < 8) {
    float s = 0.f;
    for (int c = 0; c < 16; ++c) { float v = ctrf[tid][c]; s += v * v; }
    cm2[tid][4].x = s;
  }
  __syncthreads();

  unsigned int qp[8][4];
  int minq[8];
  #pragma unroll
  for (int r = 0; r < 8; ++r) minq[r] = 65536;

  #pragma unroll
  for (int pp = 0; pp < 4; ++pp) {
    int j0 = tid + 512 * (2*pp);
    int j1 = j0 + 512;
    const float4* xj0 = (const float4*)(xb + (size_t)j0 * 16);
    const float4* xj1 = (const float4*)(xb + (size_t)j1 * 16);
    float4 a0 = xj0[0], a1 = xj0[1], a2 = xj0[2], a3 = xj0[3];
    float4 b0 = xj1[0], b1 = xj1[1], b2 = xj1[2], b3 = xj1[3];
    float va[16] = {a0.x,a0.y,a0.z,a0.w, a1.x,a1.y,a1.z,a1.w,
                    a2.x,a2.y,a2.z,a2.w, a3.x,a3.y,a3.z,a3.w};
    float vb[16] = {b0.x,b0.y,b0.z,b0.w, b1.x,b1.y,b1.z,b1.w,
                    b2.x,b2.y,b2.z,b2.w, b3.x,b3.y,b3.z,b3.w};
    float pna = 0.f, pnb = 0.f;
    #pragma unroll
    for (int c = 0; c < 16; ++c) { pna = fmaf(va[c], va[c], pna); pnb = fmaf(vb[c], vb[c], pnb); }
    #pragma unroll
    for (int r = 0; r < 8; ++r) {
      float4 m0 = cm2[r][0], m1 = cm2[r][1], m2 = cm2[r][2], m3 = cm2[r][3];
      float c2 = cm2[r][4].x;
      float wm[16] = {m0.x,m0.y,m0.z,m0.w, m1.x,m1.y,m1.z,m1.w,
                      m2.x,m2.y,m2.z,m2.w, m3.x,m3.y,m3.z,m3.w};
      float aa = pna + c2, ab = pnb + c2;
      #pragma unroll
      for (int c = 0; c < 16; ++c) { aa = fmaf(wm[c], va[c], aa); ab = fmaf(wm[c], vb[c], ab); }
      int qa = (int)(aa * 400.0f); qa = qa < 0 ? 0 : (qa > 65535 ? 65535 : qa);
      int qb = (int)(ab * 400.0f); qb = qb < 0 ? 0 : (qb > 65535 ? 65535 : qb);
      qp[r][pp] = (unsigned int)qa | ((unsigned int)qb << 16);
      minq[r] = min(minq[r], min(qa, qb));
    }
  }
  #pragma unroll
  for (int r = 0; r < 8; ++r) lmin[r][tid] = (unsigned short)minq[r];
  __syncthreads();

  int w = tid >> 6, lane = tid & 63;
  {
    unsigned short lv[8];
    #pragma unroll
    for (int t = 0; t < 8; ++t) lv[t] = lmin[w][lane + 64*t];
    int lo = 0, hi = 65535;
    #pragma unroll
    for (int it = 0; it < 16; ++it) {
      int mid = (lo + hi) >> 1;
      int cnt = 0;
      #pragma unroll
      for (int t = 0; t < 8; ++t) cnt += __popcll(__ballot((int)lv[t] <= mid));
      if (cnt >= 10) hi = mid; else lo = mid + 1;
    }
    if (lane == 0) qtS[w] = (unsigned short)min(lo + 2, 65535);
  }
  __syncthreads();

  {
    unsigned int qts[8];
    #pragma unroll
    for (int r = 0; r < 8; ++r) qts[r] = qtS[r];
    #pragma unroll
    for (int r = 0; r < 8; ++r) {
      #pragma unroll
      for (int pp = 0; pp < 4; ++pp) {
        unsigned int wq = qp[r][pp];
        unsigned int q0 = wq & 0xffffu, q1 = wq >> 16;
        if (q0 <= qts[r]) { unsigned int p = atomicAdd(&cCnt[r], 1u); if (p < 192u) cand[r][p] = tid + 512*(2*pp); }
        if (q1 <= qts[r]) { unsigned int p = atomicAdd(&cCnt[r], 1u); if (p < 192u) cand[r][p] = tid + 512*(2*pp+1); }
      }
    }
  }
  __syncthreads();

  {
    int nc = (int)cCnt[w]; if (nc > 192) nc = 192;
    double key[3]; int kid[3];
    #pragma unroll
    for (int s = 0; s < 3; ++s) {
      int c = lane + 64*s;
      if (c < nc) {
        int id = cand[w][c];
        const float4* xp = (const float4*)(xb + (size_t)id * 16);
        float4 q0 = xp[0], q1 = xp[1], q2 = xp[2], q3 = xp[3];
        float xv[16] = {q0.x,q0.y,q0.z,q0.w, q1.x,q1.y,q1.z,q1.w,
                        q2.x,q2.y,q2.z,q2.w, q3.x,q3.y,q3.z,q3.w};
        double acc = 0.0;
        #pragma unroll
        for (int c2 = 0; c2 < 16; ++c2) { double d = (double)ctrf[w][c2] - (double)xv[c2]; acc += d * d; }
        key[s] = acc; kid[s] = id;
      } else { key[s] = 1e300; kid[s] = 0x7fffffff; }
    }
    int row = rbase + w;
    for (int it = 0; it < 9; ++it) {
      double bk = key[0]; int bi = kid[0], bs = 0;
      if (key[1] < bk || (key[1] == bk && kid[1] < bi)) { bk = key[1]; bi = kid[1]; bs = 1; }
      if (key[2] < bk || (key[2] == bk && kid[2] < bi)) { bk = key[2]; bi = kid[2]; bs = 2; }
      double rk = bk; int ri = bi;
      #pragma unroll
      for (int off = 32; off > 0; off >>= 1) {
        double ok = __shfl_xor(rk, off, 64);
        int oi = __shfl_xor(ri, off, 64);
        if (ok < rk || (ok == rk && oi < ri)) { rk = ok; ri = oi; }
      }
      if (it > 0 && lane == 0) {
        idx1_i[row * 14 + it - 1] = ri;
        idx1_f[row * 14 + it - 1] = (float)ri;
      }
      if (bi == ri) key[bs] = 1e300;
    }
  }
}

// ================= K3: FPS (replicates reference's batch-0 gather) =============
__global__ __launch_bounds__(256) void fps_kernel(
    const float* __restrict__ pos, const int* __restrict__ idx_l, int* __restrict__ idx_fps)
{
  int wave = threadIdx.x >> 6, lane = threadIdx.x & 63;
  int r = blockIdx.x * 4 + wave;
  const int* il = idx_l + (size_t)r * 128;
  int gi0 = il[lane], gi1 = il[lane + 64];
  double x0 = (double)pos[gi0*3+0], y0 = (double)pos[gi0*3+1], z0 = (double)pos[gi0*3+2];
  double x1 = (double)pos[gi1*3+0], y1 = (double)pos[gi1*3+1], z1 = (double)pos[gi1*3+2];
  double d0 = 1e10, d1 = 1e10;
  int far = 0;
  int* outp = idx_fps + (size_t)r * 32;
  for (int i = 0; i < 32; ++i) {
    int ownerLane = far & 63;
    int sel = far >> 6;
    int gsel = sel ? gi1 : gi0;
    int gout = __shfl(gsel, ownerLane, 64);
    if (lane == 0) outp[i] = gout;
    double cx = __shfl(sel ? x1 : x0, ownerLane, 64);
    double cy = __shfl(sel ? y1 : y0, ownerLane, 64);
    double cz = __shfl(sel ? z1 : z0, ownerLane, 64);
    double t0 = (x0-cx)*(x0-cx) + (y0-cy)*(y0-cy) + (z0-cz)*(z0-cz);
    double t1 = (x1-cx)*(x1-cx) + (y1-cy)*(y1-cy) + (z1-cz)*(z1-cz);
    d0 = fmin(d0, t0); d1 = fmin(d1, t1);
    double v; int p;
    if (d1 > d0) { v = d1; p = lane + 64; } else { v = d0; p = lane; }
    for (int off = 32; off > 0; off >>= 1) {
      double ov = __shfl_xor(v, off, 64);
      int op = __shfl_xor(p, off, 64);
      if (ov > v || (ov == v && op < p)) { v = ov; p = op; }
    }
    far = p;
  }
}

// ========== K4a: s[gr][o] = x[gr]·W1a[o], v[gr][o] = x[gr]·(W1b-W1a)[o] ==========
__global__ __launch_bounds__(256) void sv_kernel(
    const float* __restrict__ x, const float* __restrict__ W1,
    float* __restrict__ s, float* __restrict__ v)
{
  __shared__ float xs[8][16];
  __shared__ float w1t[512], w1dt[512];
  int tid = threadIdx.x;
  int rbase = blockIdx.x * 8;
  for (int i = tid; i < 512; i += 256) {
    int c = i >> 5, o = i & 31;
    float a = W1[o * 32 + c], bb = W1[o * 32 + 16 + c];
    w1t[i] = a; w1dt[i] = bb - a;
  }
  if (tid < 128) { int rr = tid >> 4, c = tid & 15; xs[rr][c] = x[(size_t)(rbase + rr) * 16 + c]; }
  __syncthreads();
  int rr = tid >> 5, o = tid & 31;
  float sa = 0.f, va = 0.f;
  #pragma unroll
  for (int c = 0; c < 16; ++c) {
    float xv = xs[rr][c];
    sa = fmaf(xv, w1t[c * 32 + o], sa);
    va = fmaf(xv, w1dt[c * 32 + o], va);
  }
  int r = rbase + rr;
  s[(size_t)r * 32 + o] = sa;
  v[(size_t)r * 32 + o] = va;
}

// ========== K4b: h1max + h1 stats via gathered s + v ==========
__global__ __launch_bounds__(256) void h1stats_kernel(
    const float* __restrict__ s, const float* __restrict__ v, const int* __restrict__ idx1_i,
    double* __restrict__ slotsH1, float* __restrict__ h1max)
{
  __shared__ int sidx[8][14];
  __shared__ float sred[256], sred2[256];
  int tid = threadIdx.x;
  int rr = tid >> 5, o = tid & 31;
  int rbase = blockIdx.x * 8;
  if (tid < 112) { int q = tid / 14, k = tid % 14; sidx[q][k] = idx1_i[(rbase + q) * 14 + k]; }
  __syncthreads();
  int r = rbase + rr;
  int broff = r & ~4095;
  float vv = v[(size_t)r * 32 + o];
  float m = -3.4e38f, ls = 0.f, lss = 0.f;
  #pragma unroll
  for (int k = 0; k < 14; ++k) {
    int j = sidx[rr][k];
    float val = s[(size_t)(broff + j) * 32 + o] + vv;
    m = fmaxf(m, val);
    ls += val; lss += val * val;
  }
  h1max[(size_t)r * 32 + o] = m;
  sred[tid] = ls; sred2[tid] = lss;
  __syncthreads();
  if (tid < 32) {
    float s2 = 0.f, ss = 0.f;
    #pragma unroll
    for (int j = 0; j < 8; ++j) { s2 += sred[j * 32 + tid]; ss += sred2[j * 32 + tid]; }
    int slot = blockIdx.x & 255;
    atomicAdd(&slotsH1[slot * 64 + tid], (double)s2);
    atomicAdd(&slotsH1[slot * 64 + 32 + tid], (double)ss);
  }
}

// ---------------- stats finalize: scsh = [sc(C), sh(C)] ----------------
__global__ void finalize_stats_kernel(const double* __restrict__ slots, int C, double cnt,
    const float* __restrict__ g, const float* __restrict__ bta, float* __restrict__ scsh)
{
  int o = threadIdx.x;
  if (o < C) {
    double s = 0.0, ss = 0.0;
    for (int slot = 0; slot < 256; ++slot) { s += slots[slot * 2 * C + o]; ss += slots[slot * 2 * C + C + o]; }
    double mu = s / cnt;
    double var = ss / cnt - mu * mu;
    double rs = 1.0 / sqrt(var + 1e-5);
    float sc = (float)rs * g[o];
    float sh = bta[o] - (float)mu * sc;
    scsh[o] = sc;
    scsh[C + o] = sh;
  }
}

// ========== K5a: f1 = lrelu(affine(h1max)); t = f1·W2a, u = f1·(W2b-W2a) ==========
__global__ __launch_bounds__(256) void tu_kernel(
    const float* __restrict__ h1max, const float* __restrict__ scsh1, const float* __restrict__ W2,
    float* __restrict__ t, float* __restrict__ u)
{
  __shared__ float f1s[4][32];
  __shared__ float w2t[2048], w2dt[2048];
  int tid = threadIdx.x;
  int rbase = blockIdx.x * 4;
  for (int i = tid; i < 2048; i += 256) {
    int c = i >> 6, o = i & 63;
    float a = W2[o * 64 + c], bb = W2[o * 64 + 32 + c];
    w2t[i] = a; w2dt[i] = bb - a;
  }
  if (tid < 128) {
    int rr = tid >> 5, c = tid & 31;
    f1s[rr][c] = lrelu(h1max[(size_t)(rbase + rr) * 32 + c] * scsh1[c] + scsh1[32 + c]);
  }
  __syncthreads();
  int rr = tid >> 6, o = tid & 63;
  float ta = 0.f, ua = 0.f;
  #pragma unroll
  for (int c = 0; c < 32; ++c) {
    float fv = f1s[rr][c];
    ta = fmaf(fv, w2t[c * 64 + o], ta);
    ua = fmaf(fv, w2dt[c * 64 + o], ua);
  }
  int r = rbase + rr;
  t[(size_t)r * 64 + o] = ta;
  u[(size_t)r * 64 + o] = ua;
}

// ========== K5b: h2 stats via gathered t + u ==========
__global__ __launch_bounds__(256) void h2stats_kernel(
    const float* __restrict__ t, const float* __restrict__ u, const int* __restrict__ idx_fps,
    double* __restrict__ slotsH2)
{
  __shared__ int nids[8][32];
  __shared__ float sred[256], sred2[256];
  int tid = threadIdx.x;
  int o = tid & 63, wv = tid >> 6;
  int rbase = blockIdx.x * 8;
  { int q = tid >> 5, k = tid & 31; nids[q][k] = idx_fps[(rbase + q) * 32 + k]; }
  __syncthreads();
  float ls = 0.f, lss = 0.f;
  for (int rr = 0; rr < 8; ++rr) {
    int r = rbase + rr;
    int broff = r & ~4095;
    float uo = u[(size_t)r * 64 + o];
    #pragma unroll
    for (int i = 0; i < 8; ++i) {
      int k = wv + 4 * i;
      float val = t[(size_t)(broff + nids[rr][k]) * 64 + o] + uo;
      ls += val; lss += val * val;
    }
  }
  sred[tid] = ls; sred2[tid] = lss;
  __syncthreads();
  if (tid < 64) {
    float s2 = sred[tid] + sred[tid + 64] + sred[tid + 128] + sred[tid + 192];
    float ss = sred2[tid] + sred2[tid + 64] + sred2[tid + 128] + sred2[tid + 192];
    int slot = blockIdx.x & 255;
    atomicAdd(&slotsH2[slot * 128 + tid], (double)s2);
    atomicAdd(&slotsH2[slot * 128 + 64 + tid], (double)ss);
  }
}

// ========== K6: h3 = lrelu(affine(t[nid]+u))·W3ᵀ, stats + channel max ==========
#define ROWS3 8
__global__ __launch_bounds__(256, 4) void h3_kernel(
    const float* __restrict__ t, const float* __restrict__ u, const int* __restrict__ idx_fps,
    const float* __restrict__ W3, const float* __restrict__ scsh2,
    double* __restrict__ slotsH3, float* __restrict__ h3max)
{
  __shared__ float h2lds[2048];
  __shared__ float wmax[256];
  __shared__ float sred[256], sred2[256];
  __shared__ int nids[ROWS3][32];
  int tid = threadIdx.x;
  int o = tid & 63, wv = tid >> 6;
  float4 w3r[16];
  const float4* w3p = (const float4*)(W3 + o * 64);
  #pragma unroll
  for (int j = 0; j < 16; ++j) w3r[j] = w3p[j];
  float sc2o = scsh2[o], sh2o = scsh2[64 + o];
  int rbase = blockIdx.x * ROWS3;
  { int q = tid >> 5, k = tid & 31; nids[q][k] = idx_fps[(rbase + q) * 32 + k]; }
  float ls = 0.f, lss = 0.f;
  __syncthreads();
  for (int rr = 0; rr < ROWS3; ++rr) {
    int r = rbase + rr;
    int broff = r & ~4095;
    float uo = u[(size_t)r * 64 + o];
    #pragma unroll
    for (int i = 0; i < 8; ++i) {
      int k = wv + 4 * i;
      float val = t[(size_t)(broff + nids[rr][k]) * 64 + o] + uo;
      h2lds[k * 64 + o] = lrelu(val * sc2o + sh2o);
    }
    __syncthreads();
    float kmax = -3.4e38f;
    #pragma unroll
    for (int i = 0; i < 8; ++i) {
      int k = wv + 4 * i;
      const float4* hp = (const float4*)(h2lds + k * 64);
      float acc = 0.f;
      #pragma unroll
      for (int j = 0; j < 16; ++j) {
        float4 h = hp[j];
        acc = fmaf(h.x, w3r[j].x, acc); acc = fmaf(h.y, w3r[j].y, acc);
        acc = fmaf(h.z, w3r[j].z, acc); acc = fmaf(h.w, w3r[j].w, acc);
      }
      ls += acc; lss += acc * acc;
      kmax = fmaxf(kmax, acc);
    }
    wmax[tid] = kmax;
    __syncthreads();
    if (tid < 64) {
      float m = fmaxf(fmaxf(wmax[tid], wmax[64 + tid]), fmaxf(wmax[128 + tid], wmax[192 + tid]));
      h3max[(size_t)r * 64 + tid] = m;
    }
  }
  sred[tid] = ls; sred2[tid] = lss;
  __syncthreads();
  if (tid < 64) {
    float s2 = sred[tid] + sred[tid + 64] + sred[tid + 128] + sred[tid + 192];
    float ss = sred2[tid] + sred2[tid + 64] + sred2[tid + 128] + sred2[tid + 192];
    int slot = blockIdx.x & 255;
    atomicAdd(&slotsH3[slot * 128 + tid], (double)s2);
    atomicAdd(&slotsH3[slot * 128 + 64 + tid], (double)ss);
  }
}

// ---------------- K10: out = lrelu(affine(h3max)) ----------------
__global__ void out_kernel(const float* __restrict__ h3max, const float* __restrict__ scsh3,
                           float* __restrict__ out)
{
  int i = blockIdx.x * 256 + threadIdx.x;
  int o = i & 63;
  out[i] = lrelu(h3max[i] * scsh3[o] + scsh3[64 + o]);
}

extern "C" void kernel_launch(void* const* d_in, const int* in_sizes, int n_in,
                              void* d_out, int out_size, void* d_ws, size_t ws_size,
                              hipStream_t stream) {
  (void)in_sizes; (void)n_in; (void)out_size; (void)ws_size;
  const float* x   = (const float*)d_in[0];
  const float* pos = (const float*)d_in[1];
  const float* W1  = (const float*)d_in[2];
  const float* g1  = (const float*)d_in[3];
  const float* b1  = (const float*)d_in[4];
  const float* W2  = (const float*)d_in[5];
  const float* g2  = (const float*)d_in[6];
  const float* b2  = (const float*)d_in[7];
  const float* W3  = (const float*)d_in[8];
  const float* g3  = (const float*)d_in[9];
  const float* b3  = (const float*)d_in[10];

  float* out      = (float*)d_out;             // (4,4096,64) f32
  float* out_idx1 = out + 1048576;             // (4,4096,14) written as float(idx)

  char* ws = (char*)d_ws;
  double* slotsH1 = (double*)(ws + 0);         // 256 x 64 double
  double* slotsH2 = (double*)(ws + 131072);    // 256 x 128 double
  double* slotsH3 = (double*)(ws + 393216);    // 256 x 128 double
  float*  scsh1   = (float*)(ws + 655360);     // 64 f
  float*  scsh2   = (float*)(ws + 655616);     // 128 f
  float*  scsh3   = (float*)(ws + 656128);     // 128 f
  int*    idx_l   = (int*)(ws + 1048576);      // 16384 x 128 (freed after fps)
  float*  t_buf   = (float*)(ws + 1048576);    // 16384 x 64 f32 (overlaps idx_l)
  float*  u_buf   = (float*)(ws + 5242880);    // 16384 x 64 f32 (overlaps idx_l)
  int*    idx_fps = (int*)(ws + 9437184);      // 16384 x 32
  int*    idx1_i  = (int*)(ws + 11534336);     // 16384 x 14
  float*  h1max   = (float*)(ws + 12451840);   // 16384 x 32
  float*  s_buf   = (float*)(ws + 14548992);   // 16384 x 32
  float*  v_buf   = (float*)(ws + 16646144);   // 16384 x 32
  float*  h3max   = (float*)(ws + 18743296);   // 16384 x 64

  hipMemsetAsync(d_ws, 0, 656640, stream);     // zero stat accumulators

  knn_pos_kernel <<<dim3(2048), dim3(512), 0, stream>>>(pos, idx_l, idx1_i, out_idx1);
  knn_feat_kernel<<<dim3(2048), dim3(512), 0, stream>>>(x, idx1_i, out_idx1);
  fps_kernel     <<<dim3(4096), dim3(256), 0, stream>>>(pos, idx_l, idx_fps);
  // idx_l dead from here; t/u reuse its space
  sv_kernel      <<<dim3(2048), dim3(256), 0, stream>>>(x, W1, s_buf, v_buf);
  h1stats_kernel <<<dim3(2048), dim3(256), 0, stream>>>(s_buf, v_buf, idx1_i, slotsH1, h1max);
  finalize_stats_kernel<<<dim3(1), dim3(64), 0, stream>>>(slotsH1, 32, 229376.0, g1, b1, scsh1);
  tu_kernel      <<<dim3(4096), dim3(256), 0, stream>>>(h1max, scsh1, W2, t_buf, u_buf);
  h2stats_kernel <<<dim3(2048), dim3(256), 0, stream>>>(t_buf, u_buf, idx_fps, slotsH2);
  finalize_stats_kernel<<<dim3(1), dim3(64), 0, stream>>>(slotsH2, 64, 524288.0, g2, b2, scsh2);
  h3_kernel      <<<dim3(2048), dim3(256), 0, stream>>>(t_buf, u_buf, idx_fps, W3, scsh2, slotsH3, h3max);
  finalize_stats_kernel<<<dim3(1), dim3(64), 0, stream>>>(slotsH3, 64, 524288.0, g3, b3, scsh3);
  out_kernel     <<<dim3(4096), dim3(256), 0, stream>>>(h3max, scsh3, out);
}